// Round 5
// baseline (1330.831 us; speedup 1.0000x reference)
//
#include <hip/hip_runtime.h>

// TransformerBlock (attn + MLP + top2-MoE) on MI355X.
// Pre-gate chain in split-fp16 3-term MFMA (fp32-class accuracy so the MoE
// top-2 selection matches the fp32 reference); post-gate experts in plain
// fp16 MFMA, SPARSE top-2 dispatch (bitwise-equal to dense).
// R5: gemm_split BK=32 (32KB LDS -> 5 blocks/CU occupancy) + XCD-swizzled attn.

typedef _Float16 f16;
typedef _Float16 f16x4 __attribute__((ext_vector_type(4)));
typedef _Float16 f16x8 __attribute__((ext_vector_type(8)));
typedef float f32x4 __attribute__((ext_vector_type(4)));

#define MFMA16(a, b, c) __builtin_amdgcn_mfma_f32_16x16x32_f16((a), (b), (c), 0, 0, 0)

__device__ __forceinline__ void gload16(void* lds, const void* g) {
  __builtin_amdgcn_global_load_lds(
      (const __attribute__((address_space(1))) unsigned int*)g,
      (__attribute__((address_space(3))) unsigned int*)lds, 16, 0, 0);
}

__device__ __forceinline__ void split2(float t, f16& h, f16& l) {
  h = (f16)t;
  l = (f16)(t - (float)h);
}

__device__ __forceinline__ float gelu_f(float x) {  // exact (pre-gate path)
  return 0.5f * x * (1.0f + erff(x * 0.70710678118654752f));
}

__device__ __forceinline__ float gelu_fast(float x) {  // tanh-approx (post-gate experts)
  return x / (1.0f + __expf(-1.5957691216f * (x + 0.044715f * x * x * x)));
}

// ---------------- LayerNorm: one wave per row of 768; split-fp16 planes out ----------------
__global__ __launch_bounds__(256) void ln_kernel(
    const float* __restrict__ x, const float* __restrict__ gam,
    const float* __restrict__ bet, f16* __restrict__ oh, f16* __restrict__ ol) {
  const int w = threadIdx.x >> 6, lane = threadIdx.x & 63;
  const size_t row = (size_t)blockIdx.x * 4 + w;
  const float* xr = x + row * 768;
  f32x4 v[3];
  float s = 0.0f;
#pragma unroll
  for (int c = 0; c < 3; c++) {
    v[c] = *(const f32x4*)(xr + c * 256 + lane * 4);
    s += v[c][0] + v[c][1] + v[c][2] + v[c][3];
  }
#pragma unroll
  for (int off = 32; off; off >>= 1) s += __shfl_xor(s, off);
  const float mean = s * (1.0f / 768.0f);
  float q = 0.0f;
#pragma unroll
  for (int c = 0; c < 3; c++)
#pragma unroll
    for (int j = 0; j < 4; j++) {
      float d = v[c][j] - mean;
      q += d * d;
    }
#pragma unroll
  for (int off = 32; off; off >>= 1) q += __shfl_xor(q, off);
  // precise rsqrt: rsqrtf() approx (~1e-5 rel) would risk gate flips downstream
  const float rstd = 1.0f / sqrtf(q * (1.0f / 768.0f) + 1e-5f);
#pragma unroll
  for (int c = 0; c < 3; c++) {
    const int col = c * 256 + lane * 4;
    f32x4 gv = *(const f32x4*)(gam + col);
    f32x4 bv = *(const f32x4*)(bet + col);
    f16x4 yh, yl;
#pragma unroll
    for (int j = 0; j < 4; j++) {
      float y = (v[c][j] - mean) * rstd * gv[j] + bv[j];
      f16 hh, ll;
      split2(y, hh, ll);
      yh[j] = hh;
      yl[j] = ll;
    }
    *(f16x4*)(oh + row * 768 + col) = yh;
    *(f16x4*)(ol + row * 768 + col) = yl;
  }
}

// ---------------- fp32 -> split fp16 (elementwise, x4) ----------------
__global__ __launch_bounds__(256) void convert_split_k(
    const float* __restrict__ in, f16* __restrict__ oh, f16* __restrict__ ol,
    int n4) {
  const int i = blockIdx.x * 256 + threadIdx.x;
  if (i >= n4) return;
  f32x4 v = ((const f32x4*)in)[i];
  f16x4 h, l;
#pragma unroll
  for (int j = 0; j < 4; j++) {
    f16 hh, ll;
    split2(v[j], hh, ll);
    h[j] = hh;
    l[j] = ll;
  }
  ((f16x4*)oh)[i] = h;
  ((f16x4*)ol)[i] = l;
}

// ---------------- fp32 [R][ldin] (32x32 tiles) -> fp16 [C][R] (optionally split) ----------------
template <bool SPLIT>
__global__ __launch_bounds__(256) void transpose_k(
    const float* __restrict__ in, f16* __restrict__ oh, f16* __restrict__ ol,
    int R, int ldin) {
  __shared__ float t[32][33];
  const int tx = threadIdx.x & 31, ty = threadIdx.x >> 5;
  const int r0 = blockIdx.y * 32, c0 = blockIdx.x * 32;
#pragma unroll
  for (int i = 0; i < 4; i++)
    t[ty + 8 * i][tx] = in[(size_t)(r0 + ty + 8 * i) * ldin + c0 + tx];
  __syncthreads();
#pragma unroll
  for (int i = 0; i < 4; i++) {
    const float val = t[tx][ty + 8 * i];
    const size_t o = (size_t)(c0 + ty + 8 * i) * R + r0 + tx;
    if constexpr (SPLIT) {
      f16 hh, ll;
      split2(val, hh, ll);
      oh[o] = hh;
      ol[o] = ll;
    } else {
      oh[o] = (f16)val;
    }
  }
}

// ---------------- V transpose: qkv plane [T,2304] (v part) -> [B,H,64,1024] ----------------
__global__ __launch_bounds__(256) void vtrans_kernel(
    const unsigned short* __restrict__ src, unsigned short* __restrict__ dst) {
  const int nt = blockIdx.x, bh = blockIdx.y;
  const int b = bh / 12, h = bh % 12;
  __shared__ unsigned short t[64][65];
  const int tid = threadIdx.x;
#pragma unroll
  for (int i = 0; i < 16; i++) {
    const int idx = i * 256 + tid;
    const int r = idx >> 6, c = idx & 63;
    t[r][c] = src[((size_t)b * 1024 + nt * 64 + r) * 2304 + 1536 + h * 64 + c];
  }
  __syncthreads();
#pragma unroll
  for (int i = 0; i < 16; i++) {
    const int idx = i * 256 + tid;
    const int d = idx >> 6, n = idx & 63;
    dst[((size_t)bh * 64 + d) * 1024 + nt * 64 + n] = t[n][d];
  }
}

// ---------------- split-fp16 3-term GEMM: C = A·B^T (+bias), A[M,K] B[N,K] ----------------
// 128x128 tile, BK=32, 4 waves (2x2). LDS 4 planes x [128][32] f16 = 32KB
// -> 5 blocks/CU occupancy. Rows are 64B; staging lane u -> row u>>2,
// source chunk (u&3)^(row&3) (pre-swizzled global src, linear LDS dest);
// fragment read XORs the same involution: chunk = g ^ (lr&3).
// MODE 0: -> split planes (qkv)
// MODE 1: +residF -> split planes (out-proj)
// MODE 2: gelu(exact) -> split planes (mlp hidden)
// MODE 3: -> fp32 outF; addto==0: outF = (residH+residL) + v ; addto==1: outF += v
template <int MODE>
__global__ __launch_bounds__(256) void gemm_split(
    const f16* __restrict__ Ah, const f16* __restrict__ Al, int lda,
    const f16* __restrict__ Bh, const f16* __restrict__ Bl, int ldb,
    const float* __restrict__ bias, const float* __restrict__ residF,
    const f16* __restrict__ residH, const f16* __restrict__ residL, int addto,
    float* __restrict__ outF, f16* __restrict__ outH, f16* __restrict__ outL,
    int ldo, int K) {
  __shared__ __align__(16) f16 Ash[128][32];
  __shared__ __align__(16) f16 Asl[128][32];
  __shared__ __align__(16) f16 Bsh[128][32];
  __shared__ __align__(16) f16 Bsl[128][32];
  const int tid = threadIdx.x;
  const int lane = tid & 63, wid = tid >> 6;
  const int wm = wid >> 1, wn = wid & 1;
  const int g = lane >> 4, lr = lane & 15;
  const int srow = tid >> 2;                          // staging row (0..63)
  const int sch = ((tid & 3) ^ (srow & 3)) * 8;       // staged source chunk (elems)
  const size_t m0 = (size_t)blockIdx.y * 128, n0 = (size_t)blockIdx.x * 128;
  f32x4 acc[4][4] = {};
  for (int k0 = 0; k0 < K; k0 += 32) {
    __syncthreads();
#pragma unroll
    for (int s = 0; s < 2; s++) {
      const int row = srow + s * 64;   // row&3 == srow&3
      const int u = s * 256 + tid;
      const size_t ga = (m0 + row) * (size_t)lda + k0 + sch;
      const size_t gb = (n0 + row) * (size_t)ldb + k0 + sch;
      gload16(&Ash[0][0] + u * 8, Ah + ga);
      gload16(&Asl[0][0] + u * 8, Al + ga);
      gload16(&Bsh[0][0] + u * 8, Bh + gb);
      gload16(&Bsl[0][0] + u * 8, Bl + gb);
    }
    __syncthreads();
    const int cfrag = ((g ^ (lr & 3)) << 3);
    f16x8 fah[4], fal[4], fbh[4], fbl[4];
#pragma unroll
    for (int mi = 0; mi < 4; mi++) {
      const int row = wm * 64 + mi * 16 + lr;  // row&3 == lr&3
      fah[mi] = *(const f16x8*)&Ash[row][cfrag];
      fal[mi] = *(const f16x8*)&Asl[row][cfrag];
    }
#pragma unroll
    for (int ni = 0; ni < 4; ni++) {
      const int row = wn * 64 + ni * 16 + lr;
      fbh[ni] = *(const f16x8*)&Bsh[row][cfrag];
      fbl[ni] = *(const f16x8*)&Bsl[row][cfrag];
    }
#pragma unroll
    for (int mi = 0; mi < 4; mi++)
#pragma unroll
      for (int ni = 0; ni < 4; ni++) {
        acc[mi][ni] = MFMA16(fah[mi], fbh[ni], acc[mi][ni]);
        acc[mi][ni] = MFMA16(fah[mi], fbl[ni], acc[mi][ni]);
        acc[mi][ni] = MFMA16(fal[mi], fbh[ni], acc[mi][ni]);
      }
  }
#pragma unroll
  for (int ni = 0; ni < 4; ni++) {
    const size_t col = n0 + wn * 64 + ni * 16 + lr;
    const float bv = bias ? bias[col] : 0.0f;
#pragma unroll
    for (int mi = 0; mi < 4; mi++) {
      const size_t rowb = m0 + wm * 64 + mi * 16 + g * 4;
      const f32x4 c = acc[mi][ni];
#pragma unroll
      for (int r = 0; r < 4; r++) {
        const size_t idx = (rowb + r) * (size_t)ldo + col;
        const float v = c[r] + bv;
        if constexpr (MODE == 0) {
          f16 hh, ll;
          split2(v, hh, ll);
          outH[idx] = hh;
          outL[idx] = ll;
        } else if constexpr (MODE == 1) {
          const float tt = v + residF[idx];
          f16 hh, ll;
          split2(tt, hh, ll);
          outH[idx] = hh;
          outL[idx] = ll;
        } else if constexpr (MODE == 2) {
          const float tt = gelu_f(v);
          f16 hh, ll;
          split2(tt, hh, ll);
          outH[idx] = hh;
          outL[idx] = ll;
        } else {
          outF[idx] = addto ? (outF[idx] + v)
                            : ((float)residH[idx] + (float)residL[idx] + v);
        }
      }
    }
  }
}

// ---------------- sparse MoE expert GEMM 1: ehid = gelu_fast(px·w1t^T + b1) ----------------
// px [npad][768] f16 (pad rows zeroed), ew1t [3072][768], early-exit on cnt.
__global__ __launch_bounds__(256) void gemm_moe1(
    const f16* __restrict__ A, const f16* __restrict__ B,
    const float* __restrict__ bias, const int* __restrict__ cntp,
    f16* __restrict__ outH) {
  const size_t m0 = (size_t)blockIdx.y * 128, n0 = (size_t)blockIdx.x * 128;
  if ((int)m0 >= *cntp) return;
  __shared__ __align__(16) f16 As[128][64];
  __shared__ __align__(16) f16 Bs[128][64];
  const int tid = threadIdx.x;
  const int lane = tid & 63, wid = tid >> 6;
  const int wm = wid >> 1, wn = wid & 1;
  const int g = lane >> 4, lr = lane & 15;
  const int swz = (((tid & 7) ^ ((tid >> 3) & 7)) << 3);
  f32x4 acc[4][4] = {};
  for (int k0 = 0; k0 < 768; k0 += 64) {
    __syncthreads();
#pragma unroll
    for (int s = 0; s < 4; s++) {
      const int u = s * 256 + tid;
      const int row = u >> 3;
      gload16(&As[0][0] + u * 8, A + (m0 + row) * 768 + k0 + swz);
      gload16(&Bs[0][0] + u * 8, B + (n0 + row) * 768 + k0 + swz);
    }
    __syncthreads();
#pragma unroll
    for (int kk = 0; kk < 2; kk++) {
      f16x8 fa[4], fb[4];
#pragma unroll
      for (int mi = 0; mi < 4; mi++) {
        const int row = wm * 64 + mi * 16 + lr;
        fa[mi] = *(const f16x8*)&As[row][(((kk * 4 + g) ^ (lr & 7)) << 3)];
      }
#pragma unroll
      for (int ni = 0; ni < 4; ni++) {
        const int row = wn * 64 + ni * 16 + lr;
        fb[ni] = *(const f16x8*)&Bs[row][(((kk * 4 + g) ^ (lr & 7)) << 3)];
      }
#pragma unroll
      for (int mi = 0; mi < 4; mi++)
#pragma unroll
        for (int ni = 0; ni < 4; ni++)
          acc[mi][ni] = MFMA16(fa[mi], fb[ni], acc[mi][ni]);
    }
  }
#pragma unroll
  for (int ni = 0; ni < 4; ni++) {
    const size_t col = n0 + wn * 64 + ni * 16 + lr;
    const float bv = bias[col];
#pragma unroll
    for (int mi = 0; mi < 4; mi++) {
      const size_t rowb = m0 + wm * 64 + mi * 16 + g * 4;
      const f32x4 c = acc[mi][ni];
#pragma unroll
      for (int r = 0; r < 4; r++)
        outH[(rowb + r) * 3072 + col] = (f16)gelu_fast(c[r] + bv);
    }
  }
}

// ---------------- sparse MoE expert GEMM 2 + scatter: out[tok] += w*(acc+b2) ----------------
// A=ehid [npad][3072], B=ew2t [768][3072]; list/cnt route packed rows -> tokens.
__global__ __launch_bounds__(256) void gemm_moe2(
    const f16* __restrict__ A, const f16* __restrict__ B,
    const float* __restrict__ bias, const float* __restrict__ comb, int e,
    const int* __restrict__ list, const int* __restrict__ cntp,
    float* __restrict__ outF) {
  const size_t m0 = (size_t)blockIdx.y * 128, n0 = (size_t)blockIdx.x * 128;
  const int cnt = *cntp;
  if ((int)m0 >= cnt) return;
  __shared__ __align__(16) f16 As[128][64];
  __shared__ __align__(16) f16 Bs[128][64];
  const int tid = threadIdx.x;
  const int lane = tid & 63, wid = tid >> 6;
  const int wm = wid >> 1, wn = wid & 1;
  const int g = lane >> 4, lr = lane & 15;
  const int swz = (((tid & 7) ^ ((tid >> 3) & 7)) << 3);
  f32x4 acc[4][4] = {};
  for (int k0 = 0; k0 < 3072; k0 += 64) {
    __syncthreads();
#pragma unroll
    for (int s = 0; s < 4; s++) {
      const int u = s * 256 + tid;
      const int row = u >> 3;
      gload16(&As[0][0] + u * 8, A + (m0 + row) * 3072 + k0 + swz);
      gload16(&Bs[0][0] + u * 8, B + (n0 + row) * 3072 + k0 + swz);
    }
    __syncthreads();
#pragma unroll
    for (int kk = 0; kk < 2; kk++) {
      f16x8 fa[4], fb[4];
#pragma unroll
      for (int mi = 0; mi < 4; mi++) {
        const int row = wm * 64 + mi * 16 + lr;
        fa[mi] = *(const f16x8*)&As[row][(((kk * 4 + g) ^ (lr & 7)) << 3)];
      }
#pragma unroll
      for (int ni = 0; ni < 4; ni++) {
        const int row = wn * 64 + ni * 16 + lr;
        fb[ni] = *(const f16x8*)&Bs[row][(((kk * 4 + g) ^ (lr & 7)) << 3)];
      }
#pragma unroll
      for (int mi = 0; mi < 4; mi++)
#pragma unroll
        for (int ni = 0; ni < 4; ni++)
          acc[mi][ni] = MFMA16(fa[mi], fb[ni], acc[mi][ni]);
    }
  }
#pragma unroll
  for (int ni = 0; ni < 4; ni++) {
    const size_t col = n0 + wn * 64 + ni * 16 + lr;
    const float bv = bias[col];
#pragma unroll
    for (int mi = 0; mi < 4; mi++) {
      const int rowb = (int)m0 + wm * 64 + mi * 16 + g * 4;
      const f32x4 c = acc[mi][ni];
#pragma unroll
      for (int r = 0; r < 4; r++) {
        if (rowb + r < cnt) {
          const int tok = list[rowb + r];
          const float w = comb[(size_t)tok * 4 + e];
          outF[(size_t)tok * 768 + col] += w * (c[r] + bv);
        }
      }
    }
  }
}

// ---------------- flash attention, split-fp16 3-term, KVBLK=64 ----------------
// 1536 blocks, XCD-swizzled so all 16 q-tiles of one (b,h) share an XCD
// (K/V L2-resident per XCD). 4 waves x 16 q-rows. Online softmax (native exp).
__global__ __launch_bounds__(256) void attn_kernel(
    const f16* __restrict__ qh, const f16* __restrict__ ql,
    const f16* __restrict__ vth, const f16* __restrict__ vtl,
    f16* __restrict__ ch, f16* __restrict__ cl) {
  const int wg = blockIdx.y * 16 + blockIdx.x;          // 0..1535
  const int nid = (wg & 7) * 192 + (wg >> 3);           // bijective (1536%8==0)
  const int qt = nid & 15, bh = nid >> 4;
  const int b = bh / 12, h = bh % 12;
  const int tid = threadIdx.x;
  const int lane = tid & 63, w = tid >> 6;
  const int g = lane >> 4, lr = lane & 15;
  __shared__ __align__(16) f16 Ksh[64][64];
  __shared__ __align__(16) f16 Ksl[64][64];
  __shared__ __align__(16) f16 Vsh[64][64];
  __shared__ __align__(16) f16 Vsl[64][64];
  __shared__ __align__(16) char Psh[4][2048];  // per-wave P (16 x 64 f16), XOR-swizzled
  __shared__ __align__(16) char Psl[4][2048];
  const int swz = (((tid & 7) ^ ((tid >> 3) & 7)) << 3);
  const size_t qrow = (size_t)b * 1024 + qt * 64 + w * 16 + lr;
  const f16* qbh = qh + qrow * 2304 + h * 64;
  const f16* qbl = ql + qrow * 2304 + h * 64;
  const f16x8 qfh0 = *(const f16x8*)(qbh + g * 8);
  const f16x8 qfh1 = *(const f16x8*)(qbh + 32 + g * 8);
  const f16x8 qfl0 = *(const f16x8*)(qbl + g * 8);
  const f16x8 qfl1 = *(const f16x8*)(qbl + 32 + g * 8);
  f32x4 o[4] = {};
  float mrun[4], lrun[4];
#pragma unroll
  for (int r = 0; r < 4; r++) {
    mrun[r] = -1e30f;
    lrun[r] = 0.0f;
  }
  const f16* kbh = qh + ((size_t)b * 1024) * 2304 + 768 + h * 64;
  const f16* kbl = ql + ((size_t)b * 1024) * 2304 + 768 + h * 64;
  const f16* vbh = vth + (size_t)bh * 64 * 1024;
  const f16* vbl = vtl + (size_t)bh * 64 * 1024;
  char* pbh = Psh[w];
  char* pbl = Psl[w];
  for (int kv0 = 0; kv0 < 1024; kv0 += 64) {
    __syncthreads();
#pragma unroll
    for (int s = 0; s < 2; s++) {
      const int u = s * 256 + tid;  // 16B unit within an 8KB plane
      const int row = u >> 3;
      const size_t ko = (size_t)(kv0 + row) * 2304 + swz;
      gload16(&Ksh[0][0] + u * 8, kbh + ko);
      gload16(&Ksl[0][0] + u * 8, kbl + ko);
      const size_t vo = (size_t)row * 1024 + kv0 + swz;  // row = d
      gload16(&Vsh[0][0] + u * 8, vbh + vo);
      gload16(&Vsl[0][0] + u * 8, vbl + vo);
    }
    __syncthreads();
    f32x4 s[4];
    __builtin_amdgcn_s_setprio(1);
#pragma unroll
    for (int nb = 0; nb < 4; nb++) {
      const int row = nb * 16 + lr;
      const int c0 = ((g ^ (lr & 7)) << 3);
      const int c1 = (((4 + g) ^ (lr & 7)) << 3);
      const f16x8 kh0 = *(const f16x8*)&Ksh[row][c0];
      const f16x8 kh1 = *(const f16x8*)&Ksh[row][c1];
      const f16x8 kl0 = *(const f16x8*)&Ksl[row][c0];
      const f16x8 kl1 = *(const f16x8*)&Ksl[row][c1];
      f32x4 t = {};
      t = MFMA16(qfh0, kh0, t);
      t = MFMA16(qfh1, kh1, t);
      t = MFMA16(qfh0, kl0, t);
      t = MFMA16(qfh1, kl1, t);
      t = MFMA16(qfl0, kh0, t);
      t = MFMA16(qfl1, kh1, t);
      s[nb] = t;
    }
    __builtin_amdgcn_s_setprio(0);
    float tmax[4];
#pragma unroll
    for (int r = 0; r < 4; r++) tmax[r] = -1e30f;
#pragma unroll
    for (int nb = 0; nb < 4; nb++)
#pragma unroll
      for (int r = 0; r < 4; r++) {
        s[nb][r] *= 0.125f;
        tmax[r] = fmaxf(tmax[r], s[nb][r]);
      }
#pragma unroll
    for (int off = 8; off; off >>= 1)
#pragma unroll
      for (int r = 0; r < 4; r++) tmax[r] = fmaxf(tmax[r], __shfl_xor(tmax[r], off));
    float sf[4], rsum[4];
#pragma unroll
    for (int r = 0; r < 4; r++) {
      const float mn = fmaxf(mrun[r], tmax[r]);
      sf[r] = __expf(mrun[r] - mn);
      mrun[r] = mn;
      rsum[r] = 0.0f;
    }
#pragma unroll
    for (int nb = 0; nb < 4; nb++)
#pragma unroll
      for (int r = 0; r < 4; r++) {
        const float p = __expf(s[nb][r] - mrun[r]);
        s[nb][r] = p;
        rsum[r] += p;
      }
#pragma unroll
    for (int off = 8; off; off >>= 1)
#pragma unroll
      for (int r = 0; r < 4; r++) rsum[r] += __shfl_xor(rsum[r], off);
#pragma unroll
    for (int r = 0; r < 4; r++) lrun[r] = lrun[r] * sf[r] + rsum[r];
#pragma unroll
    for (int db = 0; db < 4; db++)
#pragma unroll
      for (int r = 0; r < 4; r++) o[db][r] *= sf[r];
    // P (acc layout) -> LDS (swizzled) as split fp16
#pragma unroll
    for (int nb = 0; nb < 4; nb++)
#pragma unroll
      for (int r = 0; r < 4; r++) {
        const int row = g * 4 + r;
        const int sw = ((nb * 16 + lr) * 2) ^ ((row & 7) << 4);
        f16 hh, ll;
        split2(s[nb][r], hh, ll);
        *(f16*)(pbh + row * 128 + sw) = hh;
        *(f16*)(pbl + row * 128 + sw) = ll;
      }
    // PV
    __builtin_amdgcn_s_setprio(1);
#pragma unroll
    for (int ks = 0; ks < 2; ks++) {
      const int pc = (ks * 64 + g * 16) ^ ((lr & 7) << 4);
      const f16x8 pfh = *(const f16x8*)(pbh + lr * 128 + pc);
      const f16x8 pfl = *(const f16x8*)(pbl + lr * 128 + pc);
#pragma unroll
      for (int db = 0; db < 4; db++) {
        const int vrow = db * 16 + lr;
        const int vc = (((ks * 4 + g) ^ (lr & 7)) << 3);
        const f16x8 vfh = *(const f16x8*)&Vsh[vrow][vc];
        const f16x8 vfl = *(const f16x8*)&Vsl[vrow][vc];
        o[db] = MFMA16(pfh, vfh, o[db]);
        o[db] = MFMA16(pfh, vfl, o[db]);
        o[db] = MFMA16(pfl, vfh, o[db]);
      }
    }
    __builtin_amdgcn_s_setprio(0);
  }
  const size_t orow = (size_t)b * 1024 + qt * 64 + w * 16 + g * 4;
#pragma unroll
  for (int r = 0; r < 4; r++) {
    const float inv = 1.0f / lrun[r];
#pragma unroll
    for (int db = 0; db < 4; db++) {
      const float val = o[db][r] * inv;
      const size_t oi = (orow + r) * 768 + h * 64 + db * 16 + lr;
      f16 hh, ll;
      split2(val, hh, ll);
      ch[oi] = hh;
      cl[oi] = ll;
    }
  }
}

// ---------------- gate: fp32 logits from split xm, top-2, softmax -> comb[T][4] ----------------
__global__ __launch_bounds__(256) void gate_kernel(
    const f16* __restrict__ xmh, const f16* __restrict__ xml,
    const float* __restrict__ gw, const float* __restrict__ gb,
    float* __restrict__ comb) {
  const int t = blockIdx.x * 256 + threadIdx.x;
  const f16* xrh = xmh + (size_t)t * 768;
  const f16* xrl = xml + (size_t)t * 768;
  float a0 = 0, a1 = 0, a2 = 0, a3 = 0;
  for (int k = 0; k < 768; k += 4) {
    const f16x4 xh = *(const f16x4*)(xrh + k);
    const f16x4 xl = *(const f16x4*)(xrl + k);
    const f32x4 w0 = *(const f32x4*)(gw + k);
    const f32x4 w1 = *(const f32x4*)(gw + 768 + k);
    const f32x4 w2 = *(const f32x4*)(gw + 1536 + k);
    const f32x4 w3 = *(const f32x4*)(gw + 2304 + k);
#pragma unroll
    for (int j = 0; j < 4; j++) {
      const float xv = (float)xh[j] + (float)xl[j];
      a0 += xv * w0[j];
      a1 += xv * w1[j];
      a2 += xv * w2[j];
      a3 += xv * w3[j];
    }
  }
  float l[4] = {a0 + gb[0], a1 + gb[1], a2 + gb[2], a3 + gb[3]};
  int i0 = 0;
#pragma unroll
  for (int e = 1; e < 4; e++)
    if (l[e] > l[i0]) i0 = e;  // strict > matches top_k tie order
  int i1 = -1;
#pragma unroll
  for (int e = 0; e < 4; e++)
    if (e != i0 && (i1 < 0 || l[e] > l[i1])) i1 = e;
  const float e1 = expf(l[i1] - l[i0]);
  const float inv = 1.0f / (1.0f + e1);
  float c[4] = {0.0f, 0.0f, 0.0f, 0.0f};
  c[i0] = inv;
  c[i1] = e1 * inv;
  f32x4 cv = {c[0], c[1], c[2], c[3]};
  *(f32x4*)(comb + (size_t)t * 4) = cv;
}

// ---------------- deterministic per-expert token lists (1 block, ballot scan) ----------------
__global__ __launch_bounds__(1024) void listbuild_kernel(
    const float* __restrict__ comb, int* __restrict__ lists /*[4][8192]*/,
    int* __restrict__ cnts /*[4]*/) {
  __shared__ int wsum[16];
  const int tid = threadIdx.x;
  const int lane = tid & 63, wv = tid >> 6;
  for (int e = 0; e < 4; e++) {
    int base = 0;
    for (int c = 0; c < 8; c++) {
      const int t = c * 1024 + tid;
      const int flag = comb[(size_t)t * 4 + e] > 0.0f ? 1 : 0;
      const unsigned long long mask = __ballot(flag);
      const int myrank = __popcll(mask & ((1ull << lane) - 1ull));
      if (lane == 0) wsum[wv] = __popcll(mask);
      __syncthreads();
      int wbase = 0, total = 0;
#pragma unroll
      for (int i = 0; i < 16; i++) {
        if (i < wv) wbase += wsum[i];
        total += wsum[i];
      }
      if (flag) lists[e * 8192 + base + wbase + myrank] = t;
      base += total;
      __syncthreads();
    }
    if (tid == 0) cnts[e] = base;
  }
}

// ---------------- gather xm rows into packed buffer (zero-pad to 128) ----------------
__global__ __launch_bounds__(128) void gather_kernel(
    const f16* __restrict__ xmh, const int* __restrict__ list,
    const int* __restrict__ cntp, f16* __restrict__ px) {
  const int row = blockIdx.x;
  const int cnt = *cntp;
  const int npad = (cnt + 127) & ~127;
  if (row >= npad) return;
  const int tid = threadIdx.x;
  if (tid >= 96) return;
  if (row < cnt) {
    const int t = list[row];
    *(f16x8*)(px + (size_t)row * 768 + tid * 8) =
        *(const f16x8*)(xmh + (size_t)t * 768 + tid * 8);
  } else {
    f16x8 z = {};
    *(f16x8*)(px + (size_t)row * 768 + tid * 8) = z;
  }
}

extern "C" void kernel_launch(void* const* d_in, const int* in_sizes, int n_in,
                              void* d_out, int out_size, void* d_ws,
                              size_t ws_size, hipStream_t stream) {
  const float* x = (const float*)d_in[0];
  const float* ln1g = (const float*)d_in[1];
  const float* ln1b = (const float*)d_in[2];
  const float* in_w = (const float*)d_in[3];
  const float* in_b = (const float*)d_in[4];
  const float* out_w = (const float*)d_in[5];
  const float* out_b = (const float*)d_in[6];
  const float* mlp_w1 = (const float*)d_in[7];
  const float* mlp_b1 = (const float*)d_in[8];
  const float* mlp_w2 = (const float*)d_in[9];
  const float* mlp_b2 = (const float*)d_in[10];
  const float* ln2g = (const float*)d_in[11];
  const float* ln2b = (const float*)d_in[12];
  const float* gate_w = (const float*)d_in[13];
  const float* gate_b = (const float*)d_in[14];
  const float* exp_w1 = (const float*)d_in[15];
  const float* exp_b1 = (const float*)d_in[16];
  const float* exp_w2 = (const float*)d_in[17];
  const float* exp_b2 = (const float*)d_in[18];
  float* out = (float*)d_out;
  (void)in_sizes; (void)n_in; (void)out_size;

  const size_t MB = 1ull << 20;
  if (ws_size < 130 * MB) return;  // clean absmax failure (not a crash) if ws too small
  char* ws = (char*)d_ws;
  // Region layout (lifetimes hand-verified):
  // S1 [0,24MB):   h planes -> attn ctx planes -> w1t planes -> xm planes
  // S2 [24,33MB):  in_w+out_w planes -> w2t planes
  // S3 [33,105MB): qkv planes -> mlp hid planes -> {ehid, ew1t, ew2t, px}
  // S4 [105,129MB): vt planes -> x1 planes
  // S5 [129MB..):  comb, lists, cnts
  char* S1 = ws;
  char* S2 = ws + 24 * MB;
  char* S3 = ws + 33 * MB;
  char* S4 = ws + 105 * MB;
  char* S5 = ws + 129 * MB;

  f16* h_h = (f16*)S1;                       // 12,582,912 B each
  f16* h_l = (f16*)(S1 + 12 * MB);
  f16* ctx_h = (f16*)S1;                     // after qkv gemm, h dead
  f16* ctx_l = (f16*)(S1 + 12 * MB);
  f16* w1t_h = (f16*)S1;                     // after out-proj, ctx dead
  f16* w1t_l = (f16*)(S1 + 4718592);
  f16* xmh = (f16*)S1;                       // after mlp, w1t dead
  f16* xml = (f16*)(S1 + 12 * MB);

  f16* inw_h = (f16*)S2;                     // 3,538,944 B each
  f16* inw_l = (f16*)(S2 + 3538944);
  f16* outw_h = (f16*)(S2 + 7077888);        // 1,179,648 B each
  f16* outw_l = (f16*)(S2 + 8257536);
  f16* w2t_h = (f16*)S2;                     // after out-proj, inw/outw dead
  f16* w2t_l = (f16*)(S2 + 4718592);

  f16* qkv_h = (f16*)S3;                     // 37,748,736 B each
  f16* qkv_l = (f16*)(S3 + 36 * MB);
  f16* hid_h = (f16*)S3;                     // after attn, qkv dead; [8192][1536] each
  f16* hid_l = (f16*)(S3 + 24 * MB);
  f16* ehid = (f16*)S3;                      // after mlp, hid dead; [8192][3072] = 48MB
  f16* ew1t = (f16*)(S3 + 48 * MB);          // [3072][768] f16 (4.5MB)
  f16* ew2t = (f16*)(S3 + 53 * MB);          // [768][3072] f16 (4.5MB)
  f16* px = (f16*)(S3 + 58 * MB);            // packed xm rows [8192][768] (12MB)

  f16* vt_h = (f16*)S4;                      // 12,582,912 B each
  f16* vt_l = (f16*)(S4 + 12 * MB);
  f16* x1h = (f16*)S4;                       // after attn, vt dead
  f16* x1l = (f16*)(S4 + 12 * MB);

  float* comb = (float*)S5;                  // 131,072 B
  int* lists = (int*)(S5 + 131072);          // 4 x 8192 ints (131,072 B)
  int* cnts = (int*)(S5 + 262144);           // 4 ints

  // ---- attention ----
  convert_split_k<<<dim3(1728), dim3(256), 0, stream>>>(in_w, inw_h, inw_l, 442368);
  convert_split_k<<<dim3(576), dim3(256), 0, stream>>>(out_w, outw_h, outw_l, 147456);
  ln_kernel<<<dim3(2048), dim3(256), 0, stream>>>(x, ln1g, ln1b, h_h, h_l);
  gemm_split<0><<<dim3(18, 64), dim3(256), 0, stream>>>(
      h_h, h_l, 768, inw_h, inw_l, 768, in_b, nullptr, nullptr, nullptr, 0,
      nullptr, qkv_h, qkv_l, 2304, 768);
  vtrans_kernel<<<dim3(16, 96), dim3(256), 0, stream>>>(
      (const unsigned short*)qkv_h, (unsigned short*)vt_h);
  vtrans_kernel<<<dim3(16, 96), dim3(256), 0, stream>>>(
      (const unsigned short*)qkv_l, (unsigned short*)vt_l);
  attn_kernel<<<dim3(16, 96), dim3(256), 0, stream>>>(qkv_h, qkv_l, vt_h, vt_l, ctx_h, ctx_l);
  gemm_split<1><<<dim3(6, 64), dim3(256), 0, stream>>>(
      ctx_h, ctx_l, 768, outw_h, outw_l, 768, out_b, x, nullptr, nullptr, 0,
      nullptr, x1h, x1l, 768, 768);

  // ---- MLP (hidden in two halves of 1536; result -> out (=x2, fp32)) ----
  transpose_k<true><<<dim3(96, 24), dim3(256), 0, stream>>>(mlp_w1, w1t_h, w1t_l, 768, 3072);
  transpose_k<true><<<dim3(24, 96), dim3(256), 0, stream>>>(mlp_w2, w2t_h, w2t_l, 3072, 768);
  gemm_split<2><<<dim3(12, 64), dim3(256), 0, stream>>>(
      x1h, x1l, 768, w1t_h, w1t_l, 768, mlp_b1, nullptr, nullptr, nullptr, 0,
      nullptr, hid_h, hid_l, 1536, 768);
  gemm_split<3><<<dim3(6, 64), dim3(256), 0, stream>>>(
      hid_h, hid_l, 1536, w2t_h, w2t_l, 3072, mlp_b2, nullptr, x1h, x1l, 0,
      out, nullptr, nullptr, 768, 1536);
  gemm_split<2><<<dim3(12, 64), dim3(256), 0, stream>>>(
      x1h, x1l, 768, w1t_h + (size_t)1536 * 768, w1t_l + (size_t)1536 * 768, 768,
      mlp_b1 + 1536, nullptr, nullptr, nullptr, 0, nullptr, hid_h, hid_l, 1536, 768);
  gemm_split<3><<<dim3(6, 64), dim3(256), 0, stream>>>(
      hid_h, hid_l, 1536, w2t_h + 1536, w2t_l + 1536, 3072,
      nullptr, nullptr, nullptr, nullptr, 1, out, nullptr, nullptr, 768, 1536);

  // ---- MoE (sparse top-2; bitwise-equal to dense since comb==0 terms are 0) ----
  ln_kernel<<<dim3(2048), dim3(256), 0, stream>>>(out, ln2g, ln2b, xmh, xml);
  gate_kernel<<<dim3(32), dim3(256), 0, stream>>>(xmh, xml, gate_w, gate_b, comb);
  listbuild_kernel<<<dim3(1), dim3(1024), 0, stream>>>(comb, lists, cnts);
  for (int e = 0; e < 4; e++) {
    transpose_k<false><<<dim3(96, 24), dim3(256), 0, stream>>>(
        exp_w1 + (size_t)e * 768 * 3072, ew1t, nullptr, 768, 3072);
    transpose_k<false><<<dim3(24, 96), dim3(256), 0, stream>>>(
        exp_w2 + (size_t)e * 3072 * 768, ew2t, nullptr, 3072, 768);
    gather_kernel<<<dim3(8192), dim3(128), 0, stream>>>(xmh, lists + e * 8192, cnts + e, px);
    gemm_moe1<<<dim3(24, 64), dim3(256), 0, stream>>>(
        px, ew1t, exp_b1 + e * 3072, cnts + e, ehid);
    gemm_moe2<<<dim3(6, 64), dim3(256), 0, stream>>>(
        ehid, ew2t, exp_b2 + e * 768, comb, e, lists + e * 8192, cnts + e, out);
  }
}

// Round 6
// 1167.099 us; speedup vs baseline: 1.1403x; 1.1403x over previous
//
#include <hip/hip_runtime.h>

// TransformerBlock (attn + MLP + top2-MoE) on MI355X.
// Pre-gate chain in split-fp16 3-term MFMA (fp32-class accuracy so the MoE
// top-2 selection matches the fp32 reference); post-gate experts in plain
// fp16 MFMA, SPARSE top-2 dispatch.
// R6: revert gemm_split to BK=64 (R5's BK=32 regressed: half-line fetches +
// 2x barriers); consolidated MoE: z-dim transposes, indirect-gather staging
// in moe1 (no px buffer), segment-mapped single moe1/moe2 launches + atomics.

typedef _Float16 f16;
typedef _Float16 f16x4 __attribute__((ext_vector_type(4)));
typedef _Float16 f16x8 __attribute__((ext_vector_type(8)));
typedef float f32x4 __attribute__((ext_vector_type(4)));
typedef unsigned short ushort;

#define MFMA16(a, b, c) __builtin_amdgcn_mfma_f32_16x16x32_f16((a), (b), (c), 0, 0, 0)

__device__ __forceinline__ void gload16(void* lds, const void* g) {
  __builtin_amdgcn_global_load_lds(
      (const __attribute__((address_space(1))) unsigned int*)g,
      (__attribute__((address_space(3))) unsigned int*)lds, 16, 0, 0);
}

__device__ __forceinline__ void split2(float t, f16& h, f16& l) {
  h = (f16)t;
  l = (f16)(t - (float)h);
}

__device__ __forceinline__ float gelu_f(float x) {  // exact (pre-gate path)
  return 0.5f * x * (1.0f + erff(x * 0.70710678118654752f));
}

__device__ __forceinline__ float gelu_fast(float x) {  // tanh-approx (post-gate experts)
  return x / (1.0f + __expf(-1.5957691216f * (x + 0.044715f * x * x * x)));
}

// ---------------- LayerNorm: one wave per row of 768; split-fp16 planes out ----------------
__global__ __launch_bounds__(256) void ln_kernel(
    const float* __restrict__ x, const float* __restrict__ gam,
    const float* __restrict__ bet, f16* __restrict__ oh, f16* __restrict__ ol) {
  const int w = threadIdx.x >> 6, lane = threadIdx.x & 63;
  const size_t row = (size_t)blockIdx.x * 4 + w;
  const float* xr = x + row * 768;
  f32x4 v[3];
  float s = 0.0f;
#pragma unroll
  for (int c = 0; c < 3; c++) {
    v[c] = *(const f32x4*)(xr + c * 256 + lane * 4);
    s += v[c][0] + v[c][1] + v[c][2] + v[c][3];
  }
#pragma unroll
  for (int off = 32; off; off >>= 1) s += __shfl_xor(s, off);
  const float mean = s * (1.0f / 768.0f);
  float q = 0.0f;
#pragma unroll
  for (int c = 0; c < 3; c++)
#pragma unroll
    for (int j = 0; j < 4; j++) {
      float d = v[c][j] - mean;
      q += d * d;
    }
#pragma unroll
  for (int off = 32; off; off >>= 1) q += __shfl_xor(q, off);
  // precise rsqrt: rsqrtf() approx (~1e-5 rel) would risk gate flips downstream
  const float rstd = 1.0f / sqrtf(q * (1.0f / 768.0f) + 1e-5f);
#pragma unroll
  for (int c = 0; c < 3; c++) {
    const int col = c * 256 + lane * 4;
    f32x4 gv = *(const f32x4*)(gam + col);
    f32x4 bv = *(const f32x4*)(bet + col);
    f16x4 yh, yl;
#pragma unroll
    for (int j = 0; j < 4; j++) {
      float y = (v[c][j] - mean) * rstd * gv[j] + bv[j];
      f16 hh, ll;
      split2(y, hh, ll);
      yh[j] = hh;
      yl[j] = ll;
    }
    *(f16x4*)(oh + row * 768 + col) = yh;
    *(f16x4*)(ol + row * 768 + col) = yl;
  }
}

// ---------------- fp32 -> split fp16 (elementwise, x4) ----------------
__global__ __launch_bounds__(256) void convert_split_k(
    const float* __restrict__ in, f16* __restrict__ oh, f16* __restrict__ ol,
    int n4) {
  const int i = blockIdx.x * 256 + threadIdx.x;
  if (i >= n4) return;
  f32x4 v = ((const f32x4*)in)[i];
  f16x4 h, l;
#pragma unroll
  for (int j = 0; j < 4; j++) {
    f16 hh, ll;
    split2(v[j], hh, ll);
    h[j] = hh;
    l[j] = ll;
  }
  ((f16x4*)oh)[i] = h;
  ((f16x4*)ol)[i] = l;
}

// ---------------- fp32 [R][ldin] (32x32 tiles) -> fp16 [C][R] split ----------------
__global__ __launch_bounds__(256) void transpose_k(
    const float* __restrict__ in, f16* __restrict__ oh, f16* __restrict__ ol,
    int R, int ldin) {
  __shared__ float t[32][33];
  const int tx = threadIdx.x & 31, ty = threadIdx.x >> 5;
  const int r0 = blockIdx.y * 32, c0 = blockIdx.x * 32;
#pragma unroll
  for (int i = 0; i < 4; i++)
    t[ty + 8 * i][tx] = in[(size_t)(r0 + ty + 8 * i) * ldin + c0 + tx];
  __syncthreads();
#pragma unroll
  for (int i = 0; i < 4; i++) {
    const float val = t[tx][ty + 8 * i];
    const size_t o = (size_t)(c0 + ty + 8 * i) * R + r0 + tx;
    f16 hh, ll;
    split2(val, hh, ll);
    oh[o] = hh;
    ol[o] = ll;
  }
}

// ---------------- per-expert fp32 [R][C] -> f16 [C][R] (blockIdx.z = expert) ----------------
__global__ __launch_bounds__(256) void etrans_kernel(
    const float* __restrict__ in0, f16* __restrict__ out0, int R, int C) {
  const size_t eoff = (size_t)blockIdx.z * R * C;
  const float* in = in0 + eoff;
  f16* out = out0 + eoff;
  __shared__ float t[32][33];
  const int tx = threadIdx.x & 31, ty = threadIdx.x >> 5;
  const int r0 = blockIdx.y * 32, c0 = blockIdx.x * 32;
#pragma unroll
  for (int i = 0; i < 4; i++)
    t[ty + 8 * i][tx] = in[(size_t)(r0 + ty + 8 * i) * C + c0 + tx];
  __syncthreads();
#pragma unroll
  for (int i = 0; i < 4; i++)
    out[(size_t)(c0 + ty + 8 * i) * R + r0 + tx] = (f16)t[tx][ty + 8 * i];
}

// ---------------- V transpose: qkv planes (v part) -> [B,H,64,1024]; z = hi/lo ----------------
__global__ __launch_bounds__(256) void vtrans_kernel(
    const ushort* __restrict__ srcH, const ushort* __restrict__ srcL,
    ushort* __restrict__ dstH, ushort* __restrict__ dstL) {
  const int nt = blockIdx.x, bh = blockIdx.y;
  const ushort* src = blockIdx.z ? srcL : srcH;
  ushort* dst = blockIdx.z ? dstL : dstH;
  const int b = bh / 12, h = bh % 12;
  __shared__ ushort t[64][65];
  const int tid = threadIdx.x;
#pragma unroll
  for (int i = 0; i < 16; i++) {
    const int idx = i * 256 + tid;
    const int r = idx >> 6, c = idx & 63;
    t[r][c] = src[((size_t)b * 1024 + nt * 64 + r) * 2304 + 1536 + h * 64 + c];
  }
  __syncthreads();
#pragma unroll
  for (int i = 0; i < 16; i++) {
    const int idx = i * 256 + tid;
    const int d = idx >> 6, n = idx & 63;
    dst[((size_t)bh * 64 + d) * 1024 + nt * 64 + n] = t[n][d];
  }
}

// ---------------- split-fp16 3-term GEMM: C = A·B^T (+bias), A[M,K] B[N,K] ----------------
// 128x128 tile, BK=64, 4 waves (2x2). Row-major LDS [128][64]f16 (=128B rows),
// XOR chunk-swizzle; staging: lane L -> row L>>3, global chunk (L&7)^((L>>3)&7).
// MODE 0: -> split planes (qkv)
// MODE 1: +residF -> split planes (out-proj)
// MODE 2: gelu(exact) -> split planes (mlp hidden)
// MODE 3: -> fp32 outF; addto==0: outF = (residH+residL) + v ; addto==1: outF += v
template <int MODE>
__global__ __launch_bounds__(256) void gemm_split(
    const f16* __restrict__ Ah, const f16* __restrict__ Al, int lda,
    const f16* __restrict__ Bh, const f16* __restrict__ Bl, int ldb,
    const float* __restrict__ bias, const float* __restrict__ residF,
    const f16* __restrict__ residH, const f16* __restrict__ residL, int addto,
    float* __restrict__ outF, f16* __restrict__ outH, f16* __restrict__ outL,
    int ldo, int K) {
  __shared__ __align__(16) f16 Ash[128][64];
  __shared__ __align__(16) f16 Asl[128][64];
  __shared__ __align__(16) f16 Bsh[128][64];
  __shared__ __align__(16) f16 Bsl[128][64];
  const int tid = threadIdx.x;
  const int lane = tid & 63, wid = tid >> 6;
  const int wm = wid >> 1, wn = wid & 1;
  const int g = lane >> 4, lr = lane & 15;
  const int swz = (((tid & 7) ^ ((tid >> 3) & 7)) << 3);  // element offset
  const size_t m0 = (size_t)blockIdx.y * 128, n0 = (size_t)blockIdx.x * 128;
  f32x4 acc[4][4] = {};
  for (int k0 = 0; k0 < K; k0 += 64) {
    __syncthreads();
#pragma unroll
    for (int s = 0; s < 4; s++) {
      const int u = s * 256 + tid;  // 16B unit within a 16KB plane
      const int row = u >> 3;
      const size_t ga = (m0 + row) * (size_t)lda + k0 + swz;
      const size_t gb = (n0 + row) * (size_t)ldb + k0 + swz;
      gload16(&Ash[0][0] + u * 8, Ah + ga);
      gload16(&Asl[0][0] + u * 8, Al + ga);
      gload16(&Bsh[0][0] + u * 8, Bh + gb);
      gload16(&Bsl[0][0] + u * 8, Bl + gb);
    }
    __syncthreads();
#pragma unroll
    for (int kk = 0; kk < 2; kk++) {
      f16x8 fah[4], fal[4], fbh[4], fbl[4];
#pragma unroll
      for (int mi = 0; mi < 4; mi++) {
        const int row = wm * 64 + mi * 16 + lr;
        const int c = (((kk * 4 + g) ^ (lr & 7)) << 3);
        fah[mi] = *(const f16x8*)&Ash[row][c];
        fal[mi] = *(const f16x8*)&Asl[row][c];
      }
#pragma unroll
      for (int ni = 0; ni < 4; ni++) {
        const int row = wn * 64 + ni * 16 + lr;
        const int c = (((kk * 4 + g) ^ (lr & 7)) << 3);
        fbh[ni] = *(const f16x8*)&Bsh[row][c];
        fbl[ni] = *(const f16x8*)&Bsl[row][c];
      }
#pragma unroll
      for (int mi = 0; mi < 4; mi++)
#pragma unroll
        for (int ni = 0; ni < 4; ni++) {
          acc[mi][ni] = MFMA16(fah[mi], fbh[ni], acc[mi][ni]);
          acc[mi][ni] = MFMA16(fah[mi], fbl[ni], acc[mi][ni]);
          acc[mi][ni] = MFMA16(fal[mi], fbh[ni], acc[mi][ni]);
        }
    }
  }
#pragma unroll
  for (int ni = 0; ni < 4; ni++) {
    const size_t col = n0 + wn * 64 + ni * 16 + lr;
    const float bv = bias ? bias[col] : 0.0f;
#pragma unroll
    for (int mi = 0; mi < 4; mi++) {
      const size_t rowb = m0 + wm * 64 + mi * 16 + g * 4;
      const f32x4 c = acc[mi][ni];
#pragma unroll
      for (int r = 0; r < 4; r++) {
        const size_t idx = (rowb + r) * (size_t)ldo + col;
        const float v = c[r] + bv;
        if constexpr (MODE == 0) {
          f16 hh, ll;
          split2(v, hh, ll);
          outH[idx] = hh;
          outL[idx] = ll;
        } else if constexpr (MODE == 1) {
          const float tt = v + residF[idx];
          f16 hh, ll;
          split2(tt, hh, ll);
          outH[idx] = hh;
          outL[idx] = ll;
        } else if constexpr (MODE == 2) {
          const float tt = gelu_f(v);
          f16 hh, ll;
          split2(tt, hh, ll);
          outH[idx] = hh;
          outL[idx] = ll;
        } else {
          outF[idx] = addto ? (outF[idx] + v)
                            : ((float)residH[idx] + (float)residL[idx] + v);
        }
      }
    }
  }
}

// ---------------- MoE expert GEMM 1 (all experts, segment-mapped, indirect A) ----------------
// ehid[gr][1536 half] = gelu_fast(xm[list[gr]] . w1t[e] + b1[e]); half hf.
__global__ __launch_bounds__(256) void gemm_moe1(
    const f16* __restrict__ xmh, const f16* __restrict__ etw1,
    const float* __restrict__ eb1, const int* __restrict__ lists,
    const int* __restrict__ cnts, const int* __restrict__ starts,
    f16* __restrict__ ehid, int hf) {
  const int m0 = blockIdx.y * 128;
  if (m0 >= starts[4]) return;
  int e = 0;
  while (e < 3 && m0 >= starts[e + 1]) e++;
  const int cnt = cnts[e];
  const int loc0 = m0 - starts[e];
  const int* list = lists + e * 8192;
  const f16* B = etw1 + ((size_t)e * 3072 + hf * 1536) * 768;
  const float* bias = eb1 + e * 3072 + hf * 1536;
  __shared__ __align__(16) f16 As[128][64];
  __shared__ __align__(16) f16 Bs[128][64];
  const int tid = threadIdx.x;
  const int lane = tid & 63, wid = tid >> 6;
  const int wm = wid >> 1, wn = wid & 1;
  const int g = lane >> 4, lr = lane & 15;
  const int swz = (((tid & 7) ^ ((tid >> 3) & 7)) << 3);
  const int n0 = blockIdx.x * 128;
  size_t arow[4];
#pragma unroll
  for (int s = 0; s < 4; s++) {
    const int row = (s * 256 + tid) >> 3;
    const int loc = loc0 + row;
    arow[s] = (size_t)list[loc < cnt ? loc : cnt - 1] * 768;
  }
  f32x4 acc[4][4] = {};
  for (int k0 = 0; k0 < 768; k0 += 64) {
    __syncthreads();
#pragma unroll
    for (int s = 0; s < 4; s++) {
      const int u = s * 256 + tid;
      const int row = u >> 3;
      gload16(&As[0][0] + u * 8, xmh + arow[s] + k0 + swz);
      gload16(&Bs[0][0] + u * 8, B + (size_t)(n0 + row) * 768 + k0 + swz);
    }
    __syncthreads();
#pragma unroll
    for (int kk = 0; kk < 2; kk++) {
      f16x8 fa[4], fb[4];
#pragma unroll
      for (int mi = 0; mi < 4; mi++) {
        const int row = wm * 64 + mi * 16 + lr;
        fa[mi] = *(const f16x8*)&As[row][(((kk * 4 + g) ^ (lr & 7)) << 3)];
      }
#pragma unroll
      for (int ni = 0; ni < 4; ni++) {
        const int row = wn * 64 + ni * 16 + lr;
        fb[ni] = *(const f16x8*)&Bs[row][(((kk * 4 + g) ^ (lr & 7)) << 3)];
      }
#pragma unroll
      for (int mi = 0; mi < 4; mi++)
#pragma unroll
        for (int ni = 0; ni < 4; ni++)
          acc[mi][ni] = MFMA16(fa[mi], fb[ni], acc[mi][ni]);
    }
  }
#pragma unroll
  for (int ni = 0; ni < 4; ni++) {
    const int col = n0 + wn * 64 + ni * 16 + lr;
    const float bv = bias[col];
#pragma unroll
    for (int mi = 0; mi < 4; mi++) {
      const int gr = m0 + wm * 64 + mi * 16 + g * 4;
      const f32x4 c = acc[mi][ni];
#pragma unroll
      for (int r = 0; r < 4; r++)
        ehid[(size_t)(gr + r) * 1536 + col] = (f16)gelu_fast(c[r] + bv);
    }
  }
}

// ---------------- MoE expert GEMM 2 (all experts) + atomic scatter ----------------
// out[tok] += comb[tok][e] * (ehid[gr] . w2t[e] + b2[e]); bias on hf==0 only.
__global__ __launch_bounds__(256) void gemm_moe2(
    const f16* __restrict__ ehid, const f16* __restrict__ etw2,
    const float* __restrict__ eb2, const float* __restrict__ comb,
    const int* __restrict__ lists, const int* __restrict__ cnts,
    const int* __restrict__ starts, float* __restrict__ outF, int hf) {
  const int m0 = blockIdx.y * 128;
  if (m0 >= starts[4]) return;
  int e = 0;
  while (e < 3 && m0 >= starts[e + 1]) e++;
  const int cnt = cnts[e];
  const int st = starts[e];
  const int* list = lists + e * 8192;
  const f16* B = etw2 + (size_t)e * 768 * 3072 + hf * 1536;
  __shared__ __align__(16) f16 As[128][64];
  __shared__ __align__(16) f16 Bs[128][64];
  const int tid = threadIdx.x;
  const int lane = tid & 63, wid = tid >> 6;
  const int wm = wid >> 1, wn = wid & 1;
  const int g = lane >> 4, lr = lane & 15;
  const int swz = (((tid & 7) ^ ((tid >> 3) & 7)) << 3);
  const int n0 = blockIdx.x * 128;
  f32x4 acc[4][4] = {};
  for (int k0 = 0; k0 < 1536; k0 += 64) {
    __syncthreads();
#pragma unroll
    for (int s = 0; s < 4; s++) {
      const int u = s * 256 + tid;
      const int row = u >> 3;
      gload16(&As[0][0] + u * 8, ehid + (size_t)(m0 + row) * 1536 + k0 + swz);
      gload16(&Bs[0][0] + u * 8, B + (size_t)(n0 + row) * 3072 + k0 + swz);
    }
    __syncthreads();
#pragma unroll
    for (int kk = 0; kk < 2; kk++) {
      f16x8 fa[4], fb[4];
#pragma unroll
      for (int mi = 0; mi < 4; mi++) {
        const int row = wm * 64 + mi * 16 + lr;
        fa[mi] = *(const f16x8*)&As[row][(((kk * 4 + g) ^ (lr & 7)) << 3)];
      }
#pragma unroll
      for (int ni = 0; ni < 4; ni++) {
        const int row = wn * 64 + ni * 16 + lr;
        fb[ni] = *(const f16x8*)&Bs[row][(((kk * 4 + g) ^ (lr & 7)) << 3)];
      }
#pragma unroll
      for (int mi = 0; mi < 4; mi++)
#pragma unroll
        for (int ni = 0; ni < 4; ni++)
          acc[mi][ni] = MFMA16(fa[mi], fb[ni], acc[mi][ni]);
    }
  }
#pragma unroll
  for (int ni = 0; ni < 4; ni++) {
    const int col = n0 + wn * 64 + ni * 16 + lr;
    const float bv = hf ? 0.0f : eb2[e * 768 + col];
#pragma unroll
    for (int mi = 0; mi < 4; mi++) {
      const int gr = m0 + wm * 64 + mi * 16 + g * 4;
      const f32x4 c = acc[mi][ni];
#pragma unroll
      for (int r = 0; r < 4; r++) {
        const int loc = gr + r - st;
        if (loc < cnt) {
          const int tok = list[loc];
          const float w = comb[(size_t)tok * 4 + e];
          unsafeAtomicAdd(&outF[(size_t)tok * 768 + col], w * (c[r] + bv));
        }
      }
    }
  }
}

// ---------------- flash attention, split-fp16 3-term, KVBLK=64 ----------------
// 1536 blocks, XCD-swizzled (K/V L2-resident per XCD). 4 waves x 16 q-rows.
__global__ __launch_bounds__(256) void attn_kernel(
    const f16* __restrict__ qh, const f16* __restrict__ ql,
    const f16* __restrict__ vth, const f16* __restrict__ vtl,
    f16* __restrict__ ch, f16* __restrict__ cl) {
  const int wg = blockIdx.y * 16 + blockIdx.x;          // 0..1535
  const int nid = (wg & 7) * 192 + (wg >> 3);           // bijective (1536%8==0)
  const int qt = nid & 15, bh = nid >> 4;
  const int b = bh / 12, h = bh % 12;
  const int tid = threadIdx.x;
  const int lane = tid & 63, w = tid >> 6;
  const int g = lane >> 4, lr = lane & 15;
  __shared__ __align__(16) f16 Ksh[64][64];
  __shared__ __align__(16) f16 Ksl[64][64];
  __shared__ __align__(16) f16 Vsh[64][64];
  __shared__ __align__(16) f16 Vsl[64][64];
  __shared__ __align__(16) char Psh[4][2048];  // per-wave P (16 x 64 f16), XOR-swizzled
  __shared__ __align__(16) char Psl[4][2048];
  const int swz = (((tid & 7) ^ ((tid >> 3) & 7)) << 3);
  const size_t qrow = (size_t)b * 1024 + qt * 64 + w * 16 + lr;
  const f16* qbh = qh + qrow * 2304 + h * 64;
  const f16* qbl = ql + qrow * 2304 + h * 64;
  const f16x8 qfh0 = *(const f16x8*)(qbh + g * 8);
  const f16x8 qfh1 = *(const f16x8*)(qbh + 32 + g * 8);
  const f16x8 qfl0 = *(const f16x8*)(qbl + g * 8);
  const f16x8 qfl1 = *(const f16x8*)(qbl + 32 + g * 8);
  f32x4 o[4] = {};
  float mrun[4], lrun[4];
#pragma unroll
  for (int r = 0; r < 4; r++) {
    mrun[r] = -1e30f;
    lrun[r] = 0.0f;
  }
  const f16* kbh = qh + ((size_t)b * 1024) * 2304 + 768 + h * 64;
  const f16* kbl = ql + ((size_t)b * 1024) * 2304 + 768 + h * 64;
  const f16* vbh = vth + (size_t)bh * 64 * 1024;
  const f16* vbl = vtl + (size_t)bh * 64 * 1024;
  char* pbh = Psh[w];
  char* pbl = Psl[w];
  for (int kv0 = 0; kv0 < 1024; kv0 += 64) {
    __syncthreads();
#pragma unroll
    for (int s = 0; s < 2; s++) {
      const int u = s * 256 + tid;  // 16B unit within an 8KB plane
      const int row = u >> 3;
      const size_t ko = (size_t)(kv0 + row) * 2304 + swz;
      gload16(&Ksh[0][0] + u * 8, kbh + ko);
      gload16(&Ksl[0][0] + u * 8, kbl + ko);
      const size_t vo = (size_t)row * 1024 + kv0 + swz;  // row = d
      gload16(&Vsh[0][0] + u * 8, vbh + vo);
      gload16(&Vsl[0][0] + u * 8, vbl + vo);
    }
    __syncthreads();
    f32x4 s[4];
    __builtin_amdgcn_s_setprio(1);
#pragma unroll
    for (int nb = 0; nb < 4; nb++) {
      const int row = nb * 16 + lr;
      const int c0 = ((g ^ (lr & 7)) << 3);
      const int c1 = (((4 + g) ^ (lr & 7)) << 3);
      const f16x8 kh0 = *(const f16x8*)&Ksh[row][c0];
      const f16x8 kh1 = *(const f16x8*)&Ksh[row][c1];
      const f16x8 kl0 = *(const f16x8*)&Ksl[row][c0];
      const f16x8 kl1 = *(const f16x8*)&Ksl[row][c1];
      f32x4 t = {};
      t = MFMA16(qfh0, kh0, t);
      t = MFMA16(qfh1, kh1, t);
      t = MFMA16(qfh0, kl0, t);
      t = MFMA16(qfh1, kl1, t);
      t = MFMA16(qfl0, kh0, t);
      t = MFMA16(qfl1, kh1, t);
      s[nb] = t;
    }
    __builtin_amdgcn_s_setprio(0);
    float tmax[4];
#pragma unroll
    for (int r = 0; r < 4; r++) tmax[r] = -1e30f;
#pragma unroll
    for (int nb = 0; nb < 4; nb++)
#pragma unroll
      for (int r = 0; r < 4; r++) {
        s[nb][r] *= 0.125f;
        tmax[r] = fmaxf(tmax[r], s[nb][r]);
      }
#pragma unroll
    for (int off = 8; off; off >>= 1)
#pragma unroll
      for (int r = 0; r < 4; r++) tmax[r] = fmaxf(tmax[r], __shfl_xor(tmax[r], off));
    float sf[4], rsum[4];
#pragma unroll
    for (int r = 0; r < 4; r++) {
      const float mn = fmaxf(mrun[r], tmax[r]);
      sf[r] = __expf(mrun[r] - mn);
      mrun[r] = mn;
      rsum[r] = 0.0f;
    }
#pragma unroll
    for (int nb = 0; nb < 4; nb++)
#pragma unroll
      for (int r = 0; r < 4; r++) {
        const float p = __expf(s[nb][r] - mrun[r]);
        s[nb][r] = p;
        rsum[r] += p;
      }
#pragma unroll
    for (int off = 8; off; off >>= 1)
#pragma unroll
      for (int r = 0; r < 4; r++) rsum[r] += __shfl_xor(rsum[r], off);
#pragma unroll
    for (int r = 0; r < 4; r++) lrun[r] = lrun[r] * sf[r] + rsum[r];
#pragma unroll
    for (int db = 0; db < 4; db++)
#pragma unroll
      for (int r = 0; r < 4; r++) o[db][r] *= sf[r];
    // P (acc layout) -> LDS (swizzled) as split fp16
#pragma unroll
    for (int nb = 0; nb < 4; nb++)
#pragma unroll
      for (int r = 0; r < 4; r++) {
        const int row = g * 4 + r;
        const int sw = ((nb * 16 + lr) * 2) ^ ((row & 7) << 4);
        f16 hh, ll;
        split2(s[nb][r], hh, ll);
        *(f16*)(pbh + row * 128 + sw) = hh;
        *(f16*)(pbl + row * 128 + sw) = ll;
      }
    // PV
    __builtin_amdgcn_s_setprio(1);
#pragma unroll
    for (int ks = 0; ks < 2; ks++) {
      const int pc = (ks * 64 + g * 16) ^ ((lr & 7) << 4);
      const f16x8 pfh = *(const f16x8*)(pbh + lr * 128 + pc);
      const f16x8 pfl = *(const f16x8*)(pbl + lr * 128 + pc);
#pragma unroll
      for (int db = 0; db < 4; db++) {
        const int vrow = db * 16 + lr;
        const int vc = (((ks * 4 + g) ^ (lr & 7)) << 3);
        const f16x8 vfh = *(const f16x8*)&Vsh[vrow][vc];
        const f16x8 vfl = *(const f16x8*)&Vsl[vrow][vc];
        o[db] = MFMA16(pfh, vfh, o[db]);
        o[db] = MFMA16(pfh, vfl, o[db]);
        o[db] = MFMA16(pfl, vfh, o[db]);
      }
    }
    __builtin_amdgcn_s_setprio(0);
  }
  const size_t orow = (size_t)b * 1024 + qt * 64 + w * 16 + g * 4;
#pragma unroll
  for (int r = 0; r < 4; r++) {
    const float inv = 1.0f / lrun[r];
#pragma unroll
    for (int db = 0; db < 4; db++) {
      const float val = o[db][r] * inv;
      const size_t oi = (orow + r) * 768 + h * 64 + db * 16 + lr;
      f16 hh, ll;
      split2(val, hh, ll);
      ch[oi] = hh;
      cl[oi] = ll;
    }
  }
}

// ---------------- gate: fp32 logits from split xm, top-2, softmax -> comb[T][4] ----------------
__global__ __launch_bounds__(256) void gate_kernel(
    const f16* __restrict__ xmh, const f16* __restrict__ xml,
    const float* __restrict__ gw, const float* __restrict__ gb,
    float* __restrict__ comb) {
  const int t = blockIdx.x * 256 + threadIdx.x;
  const f16* xrh = xmh + (size_t)t * 768;
  const f16* xrl = xml + (size_t)t * 768;
  float a0 = 0, a1 = 0, a2 = 0, a3 = 0;
  for (int k = 0; k < 768; k += 4) {
    const f16x4 xh = *(const f16x4*)(xrh + k);
    const f16x4 xl = *(const f16x4*)(xrl + k);
    const f32x4 w0 = *(const f32x4*)(gw + k);
    const f32x4 w1 = *(const f32x4*)(gw + 768 + k);
    const f32x4 w2 = *(const f32x4*)(gw + 1536 + k);
    const f32x4 w3 = *(const f32x4*)(gw + 2304 + k);
#pragma unroll
    for (int j = 0; j < 4; j++) {
      const float xv = (float)xh[j] + (float)xl[j];
      a0 += xv * w0[j];
      a1 += xv * w1[j];
      a2 += xv * w2[j];
      a3 += xv * w3[j];
    }
  }
  float l[4] = {a0 + gb[0], a1 + gb[1], a2 + gb[2], a3 + gb[3]};
  int i0 = 0;
#pragma unroll
  for (int e = 1; e < 4; e++)
    if (l[e] > l[i0]) i0 = e;  // strict > matches top_k tie order
  int i1 = -1;
#pragma unroll
  for (int e = 0; e < 4; e++)
    if (e != i0 && (i1 < 0 || l[e] > l[i1])) i1 = e;
  const float e1 = expf(l[i1] - l[i0]);
  const float inv = 1.0f / (1.0f + e1);
  float c[4] = {0.0f, 0.0f, 0.0f, 0.0f};
  c[i0] = inv;
  c[i1] = e1 * inv;
  f32x4 cv = {c[0], c[1], c[2], c[3]};
  *(f32x4*)(comb + (size_t)t * 4) = cv;
}

// ---------------- per-expert token lists + 128-aligned segment starts ----------------
__global__ __launch_bounds__(1024) void listbuild_kernel(
    const float* __restrict__ comb, int* __restrict__ lists /*[4][8192]*/,
    int* __restrict__ cnts /*[4]*/, int* __restrict__ starts /*[5]*/) {
  __shared__ int wsum[16];
  const int tid = threadIdx.x;
  const int lane = tid & 63, wv = tid >> 6;
  for (int e = 0; e < 4; e++) {
    int base = 0;
    for (int c = 0; c < 8; c++) {
      const int t = c * 1024 + tid;
      const int flag = comb[(size_t)t * 4 + e] > 0.0f ? 1 : 0;
      const unsigned long long mask = __ballot(flag);
      const int myrank = __popcll(mask & ((1ull << lane) - 1ull));
      if (lane == 0) wsum[wv] = __popcll(mask);
      __syncthreads();
      int wbase = 0, total = 0;
#pragma unroll
      for (int i = 0; i < 16; i++) {
        if (i < wv) wbase += wsum[i];
        total += wsum[i];
      }
      if (flag) lists[e * 8192 + base + wbase + myrank] = t;
      base += total;
      __syncthreads();
    }
    if (tid == 0) cnts[e] = base;
  }
  if (tid == 0) {
    int s = 0;
    starts[0] = 0;
#pragma unroll
    for (int e = 0; e < 4; e++) {
      s += (cnts[e] + 127) & ~127;
      starts[e + 1] = s;
    }
  }
}

extern "C" void kernel_launch(void* const* d_in, const int* in_sizes, int n_in,
                              void* d_out, int out_size, void* d_ws,
                              size_t ws_size, hipStream_t stream) {
  const float* x = (const float*)d_in[0];
  const float* ln1g = (const float*)d_in[1];
  const float* ln1b = (const float*)d_in[2];
  const float* in_w = (const float*)d_in[3];
  const float* in_b = (const float*)d_in[4];
  const float* out_w = (const float*)d_in[5];
  const float* out_b = (const float*)d_in[6];
  const float* mlp_w1 = (const float*)d_in[7];
  const float* mlp_b1 = (const float*)d_in[8];
  const float* mlp_w2 = (const float*)d_in[9];
  const float* mlp_b2 = (const float*)d_in[10];
  const float* ln2g = (const float*)d_in[11];
  const float* ln2b = (const float*)d_in[12];
  const float* gate_w = (const float*)d_in[13];
  const float* gate_b = (const float*)d_in[14];
  const float* exp_w1 = (const float*)d_in[15];
  const float* exp_b1 = (const float*)d_in[16];
  const float* exp_w2 = (const float*)d_in[17];
  const float* exp_b2 = (const float*)d_in[18];
  float* out = (float*)d_out;
  (void)in_sizes; (void)n_in; (void)out_size;

  const size_t MB = 1ull << 20;
  if (ws_size < 130 * MB) return;  // clean absmax failure (not a crash) if ws too small
  char* ws = (char*)d_ws;
  // Region layout (lifetimes hand-verified):
  // S1 [0,24MB):   h planes -> attn ctx planes -> w1t planes -> xm planes
  // S2 [24,33MB):  in_w+out_w planes -> w2t planes
  // S3 [33,105MB): qkv planes -> mlp hid planes -> {ehid 52, etw1 18}
  // S4 [105,129MB): vt planes -> x1 planes -> etw2 18
  // S5 [129MB..):  comb, lists, cnts, starts
  char* S1 = ws;
  char* S2 = ws + 24 * MB;
  char* S3 = ws + 33 * MB;
  char* S4 = ws + 105 * MB;
  char* S5 = ws + 129 * MB;

  f16* h_h = (f16*)S1;                       // 12,582,912 B each
  f16* h_l = (f16*)(S1 + 12 * MB);
  f16* ctx_h = (f16*)S1;                     // after qkv gemm, h dead
  f16* ctx_l = (f16*)(S1 + 12 * MB);
  f16* w1t_h = (f16*)S1;                     // after out-proj, ctx dead
  f16* w1t_l = (f16*)(S1 + 4718592);
  f16* xmh = (f16*)S1;                       // after mlp, w1t dead
  f16* xml = (f16*)(S1 + 12 * MB);

  f16* inw_h = (f16*)S2;                     // 3,538,944 B each
  f16* inw_l = (f16*)(S2 + 3538944);
  f16* outw_h = (f16*)(S2 + 7077888);        // 1,179,648 B each
  f16* outw_l = (f16*)(S2 + 8257536);
  f16* w2t_h = (f16*)S2;                     // after out-proj, inw/outw dead
  f16* w2t_l = (f16*)(S2 + 4718592);

  f16* qkv_h = (f16*)S3;                     // 37,748,736 B each
  f16* qkv_l = (f16*)(S3 + 36 * MB);
  f16* hid_h = (f16*)S3;                     // after attn, qkv dead; [8192][1536] each
  f16* hid_l = (f16*)(S3 + 24 * MB);
  f16* ehid = (f16*)S3;                      // after mlp: [16896][1536] f16 = 51.9MB
  f16* etw1 = (f16*)(S3 + 52 * MB);          // [4][3072][768] f16 = 18MB

  f16* vt_h = (f16*)S4;                      // 12,582,912 B each
  f16* vt_l = (f16*)(S4 + 12 * MB);
  f16* x1h = (f16*)S4;                       // after attn, vt dead
  f16* x1l = (f16*)(S4 + 12 * MB);
  f16* etw2 = (f16*)S4;                      // after mlp: [4][768][3072] f16 = 18MB

  float* comb = (float*)S5;                  // 131,072 B
  int* lists = (int*)(S5 + 131072);          // 4 x 8192 ints
  int* cnts = (int*)(S5 + 262144);           // 4 ints
  int* starts = (int*)(S5 + 262144 + 64);    // 5 ints

  // ---- attention ----
  convert_split_k<<<dim3(1728), dim3(256), 0, stream>>>(in_w, inw_h, inw_l, 442368);
  convert_split_k<<<dim3(576), dim3(256), 0, stream>>>(out_w, outw_h, outw_l, 147456);
  ln_kernel<<<dim3(2048), dim3(256), 0, stream>>>(x, ln1g, ln1b, h_h, h_l);
  gemm_split<0><<<dim3(18, 64), dim3(256), 0, stream>>>(
      h_h, h_l, 768, inw_h, inw_l, 768, in_b, nullptr, nullptr, nullptr, 0,
      nullptr, qkv_h, qkv_l, 2304, 768);
  vtrans_kernel<<<dim3(16, 96, 2), dim3(256), 0, stream>>>(
      (const ushort*)qkv_h, (const ushort*)qkv_l, (ushort*)vt_h, (ushort*)vt_l);
  attn_kernel<<<dim3(16, 96), dim3(256), 0, stream>>>(qkv_h, qkv_l, vt_h, vt_l, ctx_h, ctx_l);
  gemm_split<1><<<dim3(6, 64), dim3(256), 0, stream>>>(
      ctx_h, ctx_l, 768, outw_h, outw_l, 768, out_b, x, nullptr, nullptr, 0,
      nullptr, x1h, x1l, 768, 768);

  // ---- MLP (hidden in two halves of 1536; result -> out (=x2, fp32)) ----
  transpose_k<<<dim3(96, 24), dim3(256), 0, stream>>>(mlp_w1, w1t_h, w1t_l, 768, 3072);
  transpose_k<<<dim3(24, 96), dim3(256), 0, stream>>>(mlp_w2, w2t_h, w2t_l, 3072, 768);
  gemm_split<2><<<dim3(12, 64), dim3(256), 0, stream>>>(
      x1h, x1l, 768, w1t_h, w1t_l, 768, mlp_b1, nullptr, nullptr, nullptr, 0,
      nullptr, hid_h, hid_l, 1536, 768);
  gemm_split<3><<<dim3(6, 64), dim3(256), 0, stream>>>(
      hid_h, hid_l, 1536, w2t_h, w2t_l, 3072, mlp_b2, nullptr, x1h, x1l, 0,
      out, nullptr, nullptr, 768, 1536);
  gemm_split<2><<<dim3(12, 64), dim3(256), 0, stream>>>(
      x1h, x1l, 768, w1t_h + (size_t)1536 * 768, w1t_l + (size_t)1536 * 768, 768,
      mlp_b1 + 1536, nullptr, nullptr, nullptr, 0, nullptr, hid_h, hid_l, 1536, 768);
  gemm_split<3><<<dim3(6, 64), dim3(256), 0, stream>>>(
      hid_h, hid_l, 1536, w2t_h + 1536, w2t_l + 1536, 3072,
      nullptr, nullptr, nullptr, nullptr, 1, out, nullptr, nullptr, 768, 1536);

  // ---- MoE (sparse top-2, segment-mapped all-expert launches) ----
  ln_kernel<<<dim3(2048), dim3(256), 0, stream>>>(out, ln2g, ln2b, xmh, xml);
  gate_kernel<<<dim3(32), dim3(256), 0, stream>>>(xmh, xml, gate_w, gate_b, comb);
  listbuild_kernel<<<dim3(1), dim3(1024), 0, stream>>>(comb, lists, cnts, starts);
  etrans_kernel<<<dim3(96, 24, 4), dim3(256), 0, stream>>>(exp_w1, etw1, 768, 3072);
  etrans_kernel<<<dim3(24, 96, 4), dim3(256), 0, stream>>>(exp_w2, etw2, 3072, 768);
  for (int hf = 0; hf < 2; hf++) {
    gemm_moe1<<<dim3(12, 132), dim3(256), 0, stream>>>(
        xmh, etw1, exp_b1, lists, cnts, starts, ehid, hf);
    gemm_moe2<<<dim3(6, 132), dim3(256), 0, stream>>>(
        ehid, etw2, exp_b2, comb, lists, cnts, starts, out, hf);
  }
}

// Round 7
// 1125.907 us; speedup vs baseline: 1.1820x; 1.0366x over previous
//
#include <hip/hip_runtime.h>

// TransformerBlock (attn + MLP + top2-MoE) on MI355X.
// Pre-gate chain in split-fp16 3-term MFMA (fp32-class accuracy so the MoE
// top-2 selection matches the fp32 reference); post-gate experts in plain
// fp16 MFMA, SPARSE top-2 dispatch.
// R7: moe1/moe2 get 2-phase double-buffered staging (loads overlap MFMA,
// 1 barrier/K-step) + XCD-chunked block mapping. Everything else = R6.

typedef _Float16 f16;
typedef _Float16 f16x4 __attribute__((ext_vector_type(4)));
typedef _Float16 f16x8 __attribute__((ext_vector_type(8)));
typedef float f32x4 __attribute__((ext_vector_type(4)));
typedef unsigned short ushort;

#define MFMA16(a, b, c) __builtin_amdgcn_mfma_f32_16x16x32_f16((a), (b), (c), 0, 0, 0)

__device__ __forceinline__ void gload16(void* lds, const void* g) {
  __builtin_amdgcn_global_load_lds(
      (const __attribute__((address_space(1))) unsigned int*)g,
      (__attribute__((address_space(3))) unsigned int*)lds, 16, 0, 0);
}

__device__ __forceinline__ void split2(float t, f16& h, f16& l) {
  h = (f16)t;
  l = (f16)(t - (float)h);
}

__device__ __forceinline__ float gelu_f(float x) {  // exact (pre-gate path)
  return 0.5f * x * (1.0f + erff(x * 0.70710678118654752f));
}

__device__ __forceinline__ float gelu_fast(float x) {  // tanh-approx (post-gate experts)
  return x / (1.0f + __expf(-1.5957691216f * (x + 0.044715f * x * x * x)));
}

// ---------------- LayerNorm: one wave per row of 768; split-fp16 planes out ----------------
__global__ __launch_bounds__(256) void ln_kernel(
    const float* __restrict__ x, const float* __restrict__ gam,
    const float* __restrict__ bet, f16* __restrict__ oh, f16* __restrict__ ol) {
  const int w = threadIdx.x >> 6, lane = threadIdx.x & 63;
  const size_t row = (size_t)blockIdx.x * 4 + w;
  const float* xr = x + row * 768;
  f32x4 v[3];
  float s = 0.0f;
#pragma unroll
  for (int c = 0; c < 3; c++) {
    v[c] = *(const f32x4*)(xr + c * 256 + lane * 4);
    s += v[c][0] + v[c][1] + v[c][2] + v[c][3];
  }
#pragma unroll
  for (int off = 32; off; off >>= 1) s += __shfl_xor(s, off);
  const float mean = s * (1.0f / 768.0f);
  float q = 0.0f;
#pragma unroll
  for (int c = 0; c < 3; c++)
#pragma unroll
    for (int j = 0; j < 4; j++) {
      float d = v[c][j] - mean;
      q += d * d;
    }
#pragma unroll
  for (int off = 32; off; off >>= 1) q += __shfl_xor(q, off);
  // precise rsqrt: rsqrtf() approx (~1e-5 rel) would risk gate flips downstream
  const float rstd = 1.0f / sqrtf(q * (1.0f / 768.0f) + 1e-5f);
#pragma unroll
  for (int c = 0; c < 3; c++) {
    const int col = c * 256 + lane * 4;
    f32x4 gv = *(const f32x4*)(gam + col);
    f32x4 bv = *(const f32x4*)(bet + col);
    f16x4 yh, yl;
#pragma unroll
    for (int j = 0; j < 4; j++) {
      float y = (v[c][j] - mean) * rstd * gv[j] + bv[j];
      f16 hh, ll;
      split2(y, hh, ll);
      yh[j] = hh;
      yl[j] = ll;
    }
    *(f16x4*)(oh + row * 768 + col) = yh;
    *(f16x4*)(ol + row * 768 + col) = yl;
  }
}

// ---------------- fp32 -> split fp16 (elementwise, x4) ----------------
__global__ __launch_bounds__(256) void convert_split_k(
    const float* __restrict__ in, f16* __restrict__ oh, f16* __restrict__ ol,
    int n4) {
  const int i = blockIdx.x * 256 + threadIdx.x;
  if (i >= n4) return;
  f32x4 v = ((const f32x4*)in)[i];
  f16x4 h, l;
#pragma unroll
  for (int j = 0; j < 4; j++) {
    f16 hh, ll;
    split2(v[j], hh, ll);
    h[j] = hh;
    l[j] = ll;
  }
  ((f16x4*)oh)[i] = h;
  ((f16x4*)ol)[i] = l;
}

// ---------------- fp32 [R][ldin] (32x32 tiles) -> fp16 [C][R] split ----------------
__global__ __launch_bounds__(256) void transpose_k(
    const float* __restrict__ in, f16* __restrict__ oh, f16* __restrict__ ol,
    int R, int ldin) {
  __shared__ float t[32][33];
  const int tx = threadIdx.x & 31, ty = threadIdx.x >> 5;
  const int r0 = blockIdx.y * 32, c0 = blockIdx.x * 32;
#pragma unroll
  for (int i = 0; i < 4; i++)
    t[ty + 8 * i][tx] = in[(size_t)(r0 + ty + 8 * i) * ldin + c0 + tx];
  __syncthreads();
#pragma unroll
  for (int i = 0; i < 4; i++) {
    const float val = t[tx][ty + 8 * i];
    const size_t o = (size_t)(c0 + ty + 8 * i) * R + r0 + tx;
    f16 hh, ll;
    split2(val, hh, ll);
    oh[o] = hh;
    ol[o] = ll;
  }
}

// ---------------- per-expert fp32 [R][C] -> f16 [C][R] (blockIdx.z = expert) ----------------
__global__ __launch_bounds__(256) void etrans_kernel(
    const float* __restrict__ in0, f16* __restrict__ out0, int R, int C) {
  const size_t eoff = (size_t)blockIdx.z * R * C;
  const float* in = in0 + eoff;
  f16* out = out0 + eoff;
  __shared__ float t[32][33];
  const int tx = threadIdx.x & 31, ty = threadIdx.x >> 5;
  const int r0 = blockIdx.y * 32, c0 = blockIdx.x * 32;
#pragma unroll
  for (int i = 0; i < 4; i++)
    t[ty + 8 * i][tx] = in[(size_t)(r0 + ty + 8 * i) * C + c0 + tx];
  __syncthreads();
#pragma unroll
  for (int i = 0; i < 4; i++)
    out[(size_t)(c0 + ty + 8 * i) * R + r0 + tx] = (f16)t[tx][ty + 8 * i];
}

// ---------------- V transpose: qkv planes (v part) -> [B,H,64,1024]; z = hi/lo ----------------
__global__ __launch_bounds__(256) void vtrans_kernel(
    const ushort* __restrict__ srcH, const ushort* __restrict__ srcL,
    ushort* __restrict__ dstH, ushort* __restrict__ dstL) {
  const int nt = blockIdx.x, bh = blockIdx.y;
  const ushort* src = blockIdx.z ? srcL : srcH;
  ushort* dst = blockIdx.z ? dstL : dstH;
  const int b = bh / 12, h = bh % 12;
  __shared__ ushort t[64][65];
  const int tid = threadIdx.x;
#pragma unroll
  for (int i = 0; i < 16; i++) {
    const int idx = i * 256 + tid;
    const int r = idx >> 6, c = idx & 63;
    t[r][c] = src[((size_t)b * 1024 + nt * 64 + r) * 2304 + 1536 + h * 64 + c];
  }
  __syncthreads();
#pragma unroll
  for (int i = 0; i < 16; i++) {
    const int idx = i * 256 + tid;
    const int d = idx >> 6, n = idx & 63;
    dst[((size_t)bh * 64 + d) * 1024 + nt * 64 + n] = t[n][d];
  }
}

// ---------------- split-fp16 3-term GEMM: C = A·B^T (+bias), A[M,K] B[N,K] ----------------
// 128x128 tile, BK=64, 4 waves (2x2). Row-major LDS [128][64]f16 (=128B rows),
// XOR chunk-swizzle; staging: lane L -> row L>>3, global chunk (L&7)^((L>>3)&7).
template <int MODE>
__global__ __launch_bounds__(256) void gemm_split(
    const f16* __restrict__ Ah, const f16* __restrict__ Al, int lda,
    const f16* __restrict__ Bh, const f16* __restrict__ Bl, int ldb,
    const float* __restrict__ bias, const float* __restrict__ residF,
    const f16* __restrict__ residH, const f16* __restrict__ residL, int addto,
    float* __restrict__ outF, f16* __restrict__ outH, f16* __restrict__ outL,
    int ldo, int K) {
  __shared__ __align__(16) f16 Ash[128][64];
  __shared__ __align__(16) f16 Asl[128][64];
  __shared__ __align__(16) f16 Bsh[128][64];
  __shared__ __align__(16) f16 Bsl[128][64];
  const int tid = threadIdx.x;
  const int lane = tid & 63, wid = tid >> 6;
  const int wm = wid >> 1, wn = wid & 1;
  const int g = lane >> 4, lr = lane & 15;
  const int swz = (((tid & 7) ^ ((tid >> 3) & 7)) << 3);  // element offset
  const size_t m0 = (size_t)blockIdx.y * 128, n0 = (size_t)blockIdx.x * 128;
  f32x4 acc[4][4] = {};
  for (int k0 = 0; k0 < K; k0 += 64) {
    __syncthreads();
#pragma unroll
    for (int s = 0; s < 4; s++) {
      const int u = s * 256 + tid;  // 16B unit within a 16KB plane
      const int row = u >> 3;
      const size_t ga = (m0 + row) * (size_t)lda + k0 + swz;
      const size_t gb = (n0 + row) * (size_t)ldb + k0 + swz;
      gload16(&Ash[0][0] + u * 8, Ah + ga);
      gload16(&Asl[0][0] + u * 8, Al + ga);
      gload16(&Bsh[0][0] + u * 8, Bh + gb);
      gload16(&Bsl[0][0] + u * 8, Bl + gb);
    }
    __syncthreads();
#pragma unroll
    for (int kk = 0; kk < 2; kk++) {
      f16x8 fah[4], fal[4], fbh[4], fbl[4];
#pragma unroll
      for (int mi = 0; mi < 4; mi++) {
        const int row = wm * 64 + mi * 16 + lr;
        const int c = (((kk * 4 + g) ^ (lr & 7)) << 3);
        fah[mi] = *(const f16x8*)&Ash[row][c];
        fal[mi] = *(const f16x8*)&Asl[row][c];
      }
#pragma unroll
      for (int ni = 0; ni < 4; ni++) {
        const int row = wn * 64 + ni * 16 + lr;
        const int c = (((kk * 4 + g) ^ (lr & 7)) << 3);
        fbh[ni] = *(const f16x8*)&Bsh[row][c];
        fbl[ni] = *(const f16x8*)&Bsl[row][c];
      }
#pragma unroll
      for (int mi = 0; mi < 4; mi++)
#pragma unroll
        for (int ni = 0; ni < 4; ni++) {
          acc[mi][ni] = MFMA16(fah[mi], fbh[ni], acc[mi][ni]);
          acc[mi][ni] = MFMA16(fah[mi], fbl[ni], acc[mi][ni]);
          acc[mi][ni] = MFMA16(fal[mi], fbh[ni], acc[mi][ni]);
        }
    }
  }
#pragma unroll
  for (int ni = 0; ni < 4; ni++) {
    const size_t col = n0 + wn * 64 + ni * 16 + lr;
    const float bv = bias ? bias[col] : 0.0f;
#pragma unroll
    for (int mi = 0; mi < 4; mi++) {
      const size_t rowb = m0 + wm * 64 + mi * 16 + g * 4;
      const f32x4 c = acc[mi][ni];
#pragma unroll
      for (int r = 0; r < 4; r++) {
        const size_t idx = (rowb + r) * (size_t)ldo + col;
        const float v = c[r] + bv;
        if constexpr (MODE == 0) {
          f16 hh, ll;
          split2(v, hh, ll);
          outH[idx] = hh;
          outL[idx] = ll;
        } else if constexpr (MODE == 1) {
          const float tt = v + residF[idx];
          f16 hh, ll;
          split2(tt, hh, ll);
          outH[idx] = hh;
          outL[idx] = ll;
        } else if constexpr (MODE == 2) {
          const float tt = gelu_f(v);
          f16 hh, ll;
          split2(tt, hh, ll);
          outH[idx] = hh;
          outL[idx] = ll;
        } else {
          outF[idx] = addto ? (outF[idx] + v)
                            : ((float)residH[idx] + (float)residL[idx] + v);
        }
      }
    }
  }
}

// ---------------- MoE expert GEMM 1: 2-phase dbuf, XCD-chunked, indirect A ----------------
// 1-D grid 1584 (= 12 x 132). ehid[gr][1536] = gelu_fast(xm[list] . w1t[e] + b1).
__global__ __launch_bounds__(256) void gemm_moe1(
    const f16* __restrict__ xmh, const f16* __restrict__ etw1,
    const float* __restrict__ eb1, const int* __restrict__ lists,
    const int* __restrict__ cnts, const int* __restrict__ starts,
    f16* __restrict__ ehid, int hf) {
  const int per = gridDim.x >> 3;  // 1584/8 = 198
  const int lin = (blockIdx.x & 7) * per + (blockIdx.x >> 3);
  const int bx = lin % 12, by = lin / 12;
  const int m0 = by * 128;
  if (m0 >= starts[4]) return;
  int e = 0;
  while (e < 3 && m0 >= starts[e + 1]) e++;
  const int cnt = cnts[e];
  const int loc0 = m0 - starts[e];
  const int* list = lists + e * 8192;
  const f16* Bw = etw1 + ((size_t)e * 3072 + hf * 1536) * 768;
  const float* bias = eb1 + e * 3072 + hf * 1536;
  __shared__ __align__(16) f16 As0[128][64], Bs0[128][64];
  __shared__ __align__(16) f16 As1[128][64], Bs1[128][64];
  const int tid = threadIdx.x;
  const int lane = tid & 63, wid = tid >> 6;
  const int wm = wid >> 1, wn = wid & 1;
  const int g = lane >> 4, lr = lane & 15;
  const int swz = (((tid & 7) ^ ((tid >> 3) & 7)) << 3);
  const int n0 = bx * 128;
  size_t arow[4];
#pragma unroll
  for (int s = 0; s < 4; s++) {
    const int row = (s * 256 + tid) >> 3;
    const int loc = loc0 + row;
    arow[s] = (size_t)list[loc < cnt ? loc : cnt - 1] * 768;
  }
  f32x4 acc[4][4] = {};
  auto STAGE = [&](f16 (&A)[128][64], f16 (&B)[128][64], int k0) {
#pragma unroll
    for (int s = 0; s < 4; s++) {
      const int u = s * 256 + tid;
      const int row = u >> 3;
      gload16(&A[0][0] + u * 8, xmh + arow[s] + k0 + swz);
      gload16(&B[0][0] + u * 8, Bw + (size_t)(n0 + row) * 768 + k0 + swz);
    }
  };
  auto COMPUTE = [&](f16 (&A)[128][64], f16 (&B)[128][64]) {
#pragma unroll
    for (int kk = 0; kk < 2; kk++) {
      f16x8 fa[4], fb[4];
#pragma unroll
      for (int mi = 0; mi < 4; mi++) {
        const int row = wm * 64 + mi * 16 + lr;
        fa[mi] = *(const f16x8*)&A[row][(((kk * 4 + g) ^ (lr & 7)) << 3)];
      }
#pragma unroll
      for (int ni = 0; ni < 4; ni++) {
        const int row = wn * 64 + ni * 16 + lr;
        fb[ni] = *(const f16x8*)&B[row][(((kk * 4 + g) ^ (lr & 7)) << 3)];
      }
#pragma unroll
      for (int mi = 0; mi < 4; mi++)
#pragma unroll
        for (int ni = 0; ni < 4; ni++)
          acc[mi][ni] = MFMA16(fa[mi], fb[ni], acc[mi][ni]);
    }
  };
  STAGE(As0, Bs0, 0);
#pragma unroll
  for (int t = 0; t < 12; t += 2) {
    __syncthreads();                           // drains prev stage (overlapped)
    if (t + 1 < 12) STAGE(As1, Bs1, (t + 1) * 64);
    COMPUTE(As0, Bs0);
    __syncthreads();
    if (t + 2 < 12) STAGE(As0, Bs0, (t + 2) * 64);
    COMPUTE(As1, Bs1);
  }
#pragma unroll
  for (int ni = 0; ni < 4; ni++) {
    const int col = n0 + wn * 64 + ni * 16 + lr;
    const float bv = bias[col];
#pragma unroll
    for (int mi = 0; mi < 4; mi++) {
      const int gr = m0 + wm * 64 + mi * 16 + g * 4;
      const f32x4 c = acc[mi][ni];
#pragma unroll
      for (int r = 0; r < 4; r++)
        ehid[(size_t)(gr + r) * 1536 + col] = (f16)gelu_fast(c[r] + bv);
    }
  }
}

// ---------------- MoE expert GEMM 2: 2-phase dbuf, XCD-chunked, atomic scatter ----------------
// 1-D grid 792 (= 6 x 132). out[tok] += comb[tok][e]*(ehid . w2t[e] + b2(hf0)).
__global__ __launch_bounds__(256) void gemm_moe2(
    const f16* __restrict__ ehid, const f16* __restrict__ etw2,
    const float* __restrict__ eb2, const float* __restrict__ comb,
    const int* __restrict__ lists, const int* __restrict__ cnts,
    const int* __restrict__ starts, float* __restrict__ outF, int hf) {
  const int per = gridDim.x >> 3;  // 792/8 = 99
  const int lin = (blockIdx.x & 7) * per + (blockIdx.x >> 3);
  const int bx = lin % 6, by = lin / 6;
  const int m0 = by * 128;
  if (m0 >= starts[4]) return;
  int e = 0;
  while (e < 3 && m0 >= starts[e + 1]) e++;
  const int cnt = cnts[e];
  const int st = starts[e];
  const int* list = lists + e * 8192;
  const f16* Bw = etw2 + (size_t)e * 768 * 3072 + hf * 1536;
  __shared__ __align__(16) f16 As0[128][64], Bs0[128][64];
  __shared__ __align__(16) f16 As1[128][64], Bs1[128][64];
  const int tid = threadIdx.x;
  const int lane = tid & 63, wid = tid >> 6;
  const int wm = wid >> 1, wn = wid & 1;
  const int g = lane >> 4, lr = lane & 15;
  const int swz = (((tid & 7) ^ ((tid >> 3) & 7)) << 3);
  const int n0 = bx * 128;
  f32x4 acc[4][4] = {};
  auto STAGE = [&](f16 (&A)[128][64], f16 (&B)[128][64], int k0) {
#pragma unroll
    for (int s = 0; s < 4; s++) {
      const int u = s * 256 + tid;
      const int row = u >> 3;
      gload16(&A[0][0] + u * 8, ehid + (size_t)(m0 + row) * 1536 + k0 + swz);
      gload16(&B[0][0] + u * 8, Bw + (size_t)(n0 + row) * 3072 + k0 + swz);
    }
  };
  auto COMPUTE = [&](f16 (&A)[128][64], f16 (&B)[128][64]) {
#pragma unroll
    for (int kk = 0; kk < 2; kk++) {
      f16x8 fa[4], fb[4];
#pragma unroll
      for (int mi = 0; mi < 4; mi++) {
        const int row = wm * 64 + mi * 16 + lr;
        fa[mi] = *(const f16x8*)&A[row][(((kk * 4 + g) ^ (lr & 7)) << 3)];
      }
#pragma unroll
      for (int ni = 0; ni < 4; ni++) {
        const int row = wn * 64 + ni * 16 + lr;
        fb[ni] = *(const f16x8*)&B[row][(((kk * 4 + g) ^ (lr & 7)) << 3)];
      }
#pragma unroll
      for (int mi = 0; mi < 4; mi++)
#pragma unroll
        for (int ni = 0; ni < 4; ni++)
          acc[mi][ni] = MFMA16(fa[mi], fb[ni], acc[mi][ni]);
    }
  };
  STAGE(As0, Bs0, 0);
#pragma unroll
  for (int t = 0; t < 24; t += 2) {
    __syncthreads();                           // drains prev stage (overlapped)
    if (t + 1 < 24) STAGE(As1, Bs1, (t + 1) * 64);
    COMPUTE(As0, Bs0);
    __syncthreads();
    if (t + 2 < 24) STAGE(As0, Bs0, (t + 2) * 64);
    COMPUTE(As1, Bs1);
  }
#pragma unroll
  for (int ni = 0; ni < 4; ni++) {
    const int col = n0 + wn * 64 + ni * 16 + lr;
    const float bv = hf ? 0.0f : eb2[e * 768 + col];
#pragma unroll
    for (int mi = 0; mi < 4; mi++) {
      const int gr = m0 + wm * 64 + mi * 16 + g * 4;
      const f32x4 c = acc[mi][ni];
#pragma unroll
      for (int r = 0; r < 4; r++) {
        const int loc = gr + r - st;
        if (loc < cnt) {
          const int tok = list[loc];
          const float w = comb[(size_t)tok * 4 + e];
          unsafeAtomicAdd(&outF[(size_t)tok * 768 + col], w * (c[r] + bv));
        }
      }
    }
  }
}

// ---------------- flash attention, split-fp16 3-term, KVBLK=64 ----------------
// 1536 blocks, XCD-swizzled (K/V L2-resident per XCD). 4 waves x 16 q-rows.
__global__ __launch_bounds__(256) void attn_kernel(
    const f16* __restrict__ qh, const f16* __restrict__ ql,
    const f16* __restrict__ vth, const f16* __restrict__ vtl,
    f16* __restrict__ ch, f16* __restrict__ cl) {
  const int wg = blockIdx.y * 16 + blockIdx.x;          // 0..1535
  const int nid = (wg & 7) * 192 + (wg >> 3);           // bijective (1536%8==0)
  const int qt = nid & 15, bh = nid >> 4;
  const int b = bh / 12, h = bh % 12;
  const int tid = threadIdx.x;
  const int lane = tid & 63, w = tid >> 6;
  const int g = lane >> 4, lr = lane & 15;
  __shared__ __align__(16) f16 Ksh[64][64];
  __shared__ __align__(16) f16 Ksl[64][64];
  __shared__ __align__(16) f16 Vsh[64][64];
  __shared__ __align__(16) f16 Vsl[64][64];
  __shared__ __align__(16) char Psh[4][2048];  // per-wave P (16 x 64 f16), XOR-swizzled
  __shared__ __align__(16) char Psl[4][2048];
  const int swz = (((tid & 7) ^ ((tid >> 3) & 7)) << 3);
  const size_t qrow = (size_t)b * 1024 + qt * 64 + w * 16 + lr;
  const f16* qbh = qh + qrow * 2304 + h * 64;
  const f16* qbl = ql + qrow * 2304 + h * 64;
  const f16x8 qfh0 = *(const f16x8*)(qbh + g * 8);
  const f16x8 qfh1 = *(const f16x8*)(qbh + 32 + g * 8);
  const f16x8 qfl0 = *(const f16x8*)(qbl + g * 8);
  const f16x8 qfl1 = *(const f16x8*)(qbl + 32 + g * 8);
  f32x4 o[4] = {};
  float mrun[4], lrun[4];
#pragma unroll
  for (int r = 0; r < 4; r++) {
    mrun[r] = -1e30f;
    lrun[r] = 0.0f;
  }
  const f16* kbh = qh + ((size_t)b * 1024) * 2304 + 768 + h * 64;
  const f16* kbl = ql + ((size_t)b * 1024) * 2304 + 768 + h * 64;
  const f16* vbh = vth + (size_t)bh * 64 * 1024;
  const f16* vbl = vtl + (size_t)bh * 64 * 1024;
  char* pbh = Psh[w];
  char* pbl = Psl[w];
  for (int kv0 = 0; kv0 < 1024; kv0 += 64) {
    __syncthreads();
#pragma unroll
    for (int s = 0; s < 2; s++) {
      const int u = s * 256 + tid;  // 16B unit within an 8KB plane
      const int row = u >> 3;
      const size_t ko = (size_t)(kv0 + row) * 2304 + swz;
      gload16(&Ksh[0][0] + u * 8, kbh + ko);
      gload16(&Ksl[0][0] + u * 8, kbl + ko);
      const size_t vo = (size_t)row * 1024 + kv0 + swz;  // row = d
      gload16(&Vsh[0][0] + u * 8, vbh + vo);
      gload16(&Vsl[0][0] + u * 8, vbl + vo);
    }
    __syncthreads();
    f32x4 s[4];
    __builtin_amdgcn_s_setprio(1);
#pragma unroll
    for (int nb = 0; nb < 4; nb++) {
      const int row = nb * 16 + lr;
      const int c0 = ((g ^ (lr & 7)) << 3);
      const int c1 = (((4 + g) ^ (lr & 7)) << 3);
      const f16x8 kh0 = *(const f16x8*)&Ksh[row][c0];
      const f16x8 kh1 = *(const f16x8*)&Ksh[row][c1];
      const f16x8 kl0 = *(const f16x8*)&Ksl[row][c0];
      const f16x8 kl1 = *(const f16x8*)&Ksl[row][c1];
      f32x4 t = {};
      t = MFMA16(qfh0, kh0, t);
      t = MFMA16(qfh1, kh1, t);
      t = MFMA16(qfh0, kl0, t);
      t = MFMA16(qfh1, kl1, t);
      t = MFMA16(qfl0, kh0, t);
      t = MFMA16(qfl1, kh1, t);
      s[nb] = t;
    }
    __builtin_amdgcn_s_setprio(0);
    float tmax[4];
#pragma unroll
    for (int r = 0; r < 4; r++) tmax[r] = -1e30f;
#pragma unroll
    for (int nb = 0; nb < 4; nb++)
#pragma unroll
      for (int r = 0; r < 4; r++) {
        s[nb][r] *= 0.125f;
        tmax[r] = fmaxf(tmax[r], s[nb][r]);
      }
#pragma unroll
    for (int off = 8; off; off >>= 1)
#pragma unroll
      for (int r = 0; r < 4; r++) tmax[r] = fmaxf(tmax[r], __shfl_xor(tmax[r], off));
    float sf[4], rsum[4];
#pragma unroll
    for (int r = 0; r < 4; r++) {
      const float mn = fmaxf(mrun[r], tmax[r]);
      sf[r] = __expf(mrun[r] - mn);
      mrun[r] = mn;
      rsum[r] = 0.0f;
    }
#pragma unroll
    for (int nb = 0; nb < 4; nb++)
#pragma unroll
      for (int r = 0; r < 4; r++) {
        const float p = __expf(s[nb][r] - mrun[r]);
        s[nb][r] = p;
        rsum[r] += p;
      }
#pragma unroll
    for (int off = 8; off; off >>= 1)
#pragma unroll
      for (int r = 0; r < 4; r++) rsum[r] += __shfl_xor(rsum[r], off);
#pragma unroll
    for (int r = 0; r < 4; r++) lrun[r] = lrun[r] * sf[r] + rsum[r];
#pragma unroll
    for (int db = 0; db < 4; db++)
#pragma unroll
      for (int r = 0; r < 4; r++) o[db][r] *= sf[r];
    // P (acc layout) -> LDS (swizzled) as split fp16
#pragma unroll
    for (int nb = 0; nb < 4; nb++)
#pragma unroll
      for (int r = 0; r < 4; r++) {
        const int row = g * 4 + r;
        const int sw = ((nb * 16 + lr) * 2) ^ ((row & 7) << 4);
        f16 hh, ll;
        split2(s[nb][r], hh, ll);
        *(f16*)(pbh + row * 128 + sw) = hh;
        *(f16*)(pbl + row * 128 + sw) = ll;
      }
    // PV
    __builtin_amdgcn_s_setprio(1);
#pragma unroll
    for (int ks = 0; ks < 2; ks++) {
      const int pc = (ks * 64 + g * 16) ^ ((lr & 7) << 4);
      const f16x8 pfh = *(const f16x8*)(pbh + lr * 128 + pc);
      const f16x8 pfl = *(const f16x8*)(pbl + lr * 128 + pc);
#pragma unroll
      for (int db = 0; db < 4; db++) {
        const int vrow = db * 16 + lr;
        const int vc = (((ks * 4 + g) ^ (lr & 7)) << 3);
        const f16x8 vfh = *(const f16x8*)&Vsh[vrow][vc];
        const f16x8 vfl = *(const f16x8*)&Vsl[vrow][vc];
        o[db] = MFMA16(pfh, vfh, o[db]);
        o[db] = MFMA16(pfh, vfl, o[db]);
        o[db] = MFMA16(pfl, vfh, o[db]);
      }
    }
    __builtin_amdgcn_s_setprio(0);
  }
  const size_t orow = (size_t)b * 1024 + qt * 64 + w * 16 + g * 4;
#pragma unroll
  for (int r = 0; r < 4; r++) {
    const float inv = 1.0f / lrun[r];
#pragma unroll
    for (int db = 0; db < 4; db++) {
      const float val = o[db][r] * inv;
      const size_t oi = (orow + r) * 768 + h * 64 + db * 16 + lr;
      f16 hh, ll;
      split2(val, hh, ll);
      ch[oi] = hh;
      cl[oi] = ll;
    }
  }
}

// ---------------- gate: fp32 logits from split xm, top-2, softmax -> comb[T][4] ----------------
__global__ __launch_bounds__(256) void gate_kernel(
    const f16* __restrict__ xmh, const f16* __restrict__ xml,
    const float* __restrict__ gw, const float* __restrict__ gb,
    float* __restrict__ comb) {
  const int t = blockIdx.x * 256 + threadIdx.x;
  const f16* xrh = xmh + (size_t)t * 768;
  const f16* xrl = xml + (size_t)t * 768;
  float a0 = 0, a1 = 0, a2 = 0, a3 = 0;
  for (int k = 0; k < 768; k += 4) {
    const f16x4 xh = *(const f16x4*)(xrh + k);
    const f16x4 xl = *(const f16x4*)(xrl + k);
    const f32x4 w0 = *(const f32x4*)(gw + k);
    const f32x4 w1 = *(const f32x4*)(gw + 768 + k);
    const f32x4 w2 = *(const f32x4*)(gw + 1536 + k);
    const f32x4 w3 = *(const f32x4*)(gw + 2304 + k);
#pragma unroll
    for (int j = 0; j < 4; j++) {
      const float xv = (float)xh[j] + (float)xl[j];
      a0 += xv * w0[j];
      a1 += xv * w1[j];
      a2 += xv * w2[j];
      a3 += xv * w3[j];
    }
  }
  float l[4] = {a0 + gb[0], a1 + gb[1], a2 + gb[2], a3 + gb[3]};
  int i0 = 0;
#pragma unroll
  for (int e = 1; e < 4; e++)
    if (l[e] > l[i0]) i0 = e;  // strict > matches top_k tie order
  int i1 = -1;
#pragma unroll
  for (int e = 0; e < 4; e++)
    if (e != i0 && (i1 < 0 || l[e] > l[i1])) i1 = e;
  const float e1 = expf(l[i1] - l[i0]);
  const float inv = 1.0f / (1.0f + e1);
  float c[4] = {0.0f, 0.0f, 0.0f, 0.0f};
  c[i0] = inv;
  c[i1] = e1 * inv;
  f32x4 cv = {c[0], c[1], c[2], c[3]};
  *(f32x4*)(comb + (size_t)t * 4) = cv;
}

// ---------------- per-expert token lists + 128-aligned segment starts ----------------
__global__ __launch_bounds__(1024) void listbuild_kernel(
    const float* __restrict__ comb, int* __restrict__ lists /*[4][8192]*/,
    int* __restrict__ cnts /*[4]*/, int* __restrict__ starts /*[5]*/) {
  __shared__ int wsum[16];
  const int tid = threadIdx.x;
  const int lane = tid & 63, wv = tid >> 6;
  for (int e = 0; e < 4; e++) {
    int base = 0;
    for (int c = 0; c < 8; c++) {
      const int t = c * 1024 + tid;
      const int flag = comb[(size_t)t * 4 + e] > 0.0f ? 1 : 0;
      const unsigned long long mask = __ballot(flag);
      const int myrank = __popcll(mask & ((1ull << lane) - 1ull));
      if (lane == 0) wsum[wv] = __popcll(mask);
      __syncthreads();
      int wbase = 0, total = 0;
#pragma unroll
      for (int i = 0; i < 16; i++) {
        if (i < wv) wbase += wsum[i];
        total += wsum[i];
      }
      if (flag) lists[e * 8192 + base + wbase + myrank] = t;
      base += total;
      __syncthreads();
    }
    if (tid == 0) cnts[e] = base;
  }
  if (tid == 0) {
    int s = 0;
    starts[0] = 0;
#pragma unroll
    for (int e = 0; e < 4; e++) {
      s += (cnts[e] + 127) & ~127;
      starts[e + 1] = s;
    }
  }
}

extern "C" void kernel_launch(void* const* d_in, const int* in_sizes, int n_in,
                              void* d_out, int out_size, void* d_ws,
                              size_t ws_size, hipStream_t stream) {
  const float* x = (const float*)d_in[0];
  const float* ln1g = (const float*)d_in[1];
  const float* ln1b = (const float*)d_in[2];
  const float* in_w = (const float*)d_in[3];
  const float* in_b = (const float*)d_in[4];
  const float* out_w = (const float*)d_in[5];
  const float* out_b = (const float*)d_in[6];
  const float* mlp_w1 = (const float*)d_in[7];
  const float* mlp_b1 = (const float*)d_in[8];
  const float* mlp_w2 = (const float*)d_in[9];
  const float* mlp_b2 = (const float*)d_in[10];
  const float* ln2g = (const float*)d_in[11];
  const float* ln2b = (const float*)d_in[12];
  const float* gate_w = (const float*)d_in[13];
  const float* gate_b = (const float*)d_in[14];
  const float* exp_w1 = (const float*)d_in[15];
  const float* exp_b1 = (const float*)d_in[16];
  const float* exp_w2 = (const float*)d_in[17];
  const float* exp_b2 = (const float*)d_in[18];
  float* out = (float*)d_out;
  (void)in_sizes; (void)n_in; (void)out_size;

  const size_t MB = 1ull << 20;
  if (ws_size < 130 * MB) return;  // clean absmax failure (not a crash) if ws too small
  char* ws = (char*)d_ws;
  // Region layout (lifetimes hand-verified):
  // S1 [0,24MB):   h planes -> attn ctx planes -> w1t planes -> xm planes
  // S2 [24,33MB):  in_w+out_w planes -> w2t planes
  // S3 [33,105MB): qkv planes -> mlp hid planes -> {ehid 52, etw1 18}
  // S4 [105,129MB): vt planes -> x1 planes -> etw2 18
  // S5 [129MB..):  comb, lists, cnts, starts
  char* S1 = ws;
  char* S2 = ws + 24 * MB;
  char* S3 = ws + 33 * MB;
  char* S4 = ws + 105 * MB;
  char* S5 = ws + 129 * MB;

  f16* h_h = (f16*)S1;                       // 12,582,912 B each
  f16* h_l = (f16*)(S1 + 12 * MB);
  f16* ctx_h = (f16*)S1;                     // after qkv gemm, h dead
  f16* ctx_l = (f16*)(S1 + 12 * MB);
  f16* w1t_h = (f16*)S1;                     // after out-proj, ctx dead
  f16* w1t_l = (f16*)(S1 + 4718592);
  f16* xmh = (f16*)S1;                       // after mlp, w1t dead
  f16* xml = (f16*)(S1 + 12 * MB);

  f16* inw_h = (f16*)S2;                     // 3,538,944 B each
  f16* inw_l = (f16*)(S2 + 3538944);
  f16* outw_h = (f16*)(S2 + 7077888);        // 1,179,648 B each
  f16* outw_l = (f16*)(S2 + 8257536);
  f16* w2t_h = (f16*)S2;                     // after out-proj, inw/outw dead
  f16* w2t_l = (f16*)(S2 + 4718592);

  f16* qkv_h = (f16*)S3;                     // 37,748,736 B each
  f16* qkv_l = (f16*)(S3 + 36 * MB);
  f16* hid_h = (f16*)S3;                     // after attn, qkv dead; [8192][1536] each
  f16* hid_l = (f16*)(S3 + 24 * MB);
  f16* ehid = (f16*)S3;                      // after mlp: [16896][1536] f16 = 51.9MB
  f16* etw1 = (f16*)(S3 + 52 * MB);          // [4][3072][768] f16 = 18MB

  f16* vt_h = (f16*)S4;                      // 12,582,912 B each
  f16* vt_l = (f16*)(S4 + 12 * MB);
  f16* x1h = (f16*)S4;                       // after attn, vt dead
  f16* x1l = (f16*)(S4 + 12 * MB);
  f16* etw2 = (f16*)S4;                      // after mlp: [4][768][3072] f16 = 18MB

  float* comb = (float*)S5;                  // 131,072 B
  int* lists = (int*)(S5 + 131072);          // 4 x 8192 ints
  int* cnts = (int*)(S5 + 262144);           // 4 ints
  int* starts = (int*)(S5 + 262144 + 64);    // 5 ints

  // ---- attention ----
  convert_split_k<<<dim3(1728), dim3(256), 0, stream>>>(in_w, inw_h, inw_l, 442368);
  convert_split_k<<<dim3(576), dim3(256), 0, stream>>>(out_w, outw_h, outw_l, 147456);
  ln_kernel<<<dim3(2048), dim3(256), 0, stream>>>(x, ln1g, ln1b, h_h, h_l);
  gemm_split<0><<<dim3(18, 64), dim3(256), 0, stream>>>(
      h_h, h_l, 768, inw_h, inw_l, 768, in_b, nullptr, nullptr, nullptr, 0,
      nullptr, qkv_h, qkv_l, 2304, 768);
  vtrans_kernel<<<dim3(16, 96, 2), dim3(256), 0, stream>>>(
      (const ushort*)qkv_h, (const ushort*)qkv_l, (ushort*)vt_h, (ushort*)vt_l);
  attn_kernel<<<dim3(16, 96), dim3(256), 0, stream>>>(qkv_h, qkv_l, vt_h, vt_l, ctx_h, ctx_l);
  gemm_split<1><<<dim3(6, 64), dim3(256), 0, stream>>>(
      ctx_h, ctx_l, 768, outw_h, outw_l, 768, out_b, x, nullptr, nullptr, 0,
      nullptr, x1h, x1l, 768, 768);

  // ---- MLP (hidden in two halves of 1536; result -> out (=x2, fp32)) ----
  transpose_k<<<dim3(96, 24), dim3(256), 0, stream>>>(mlp_w1, w1t_h, w1t_l, 768, 3072);
  transpose_k<<<dim3(24, 96), dim3(256), 0, stream>>>(mlp_w2, w2t_h, w2t_l, 3072, 768);
  gemm_split<2><<<dim3(12, 64), dim3(256), 0, stream>>>(
      x1h, x1l, 768, w1t_h, w1t_l, 768, mlp_b1, nullptr, nullptr, nullptr, 0,
      nullptr, hid_h, hid_l, 1536, 768);
  gemm_split<3><<<dim3(6, 64), dim3(256), 0, stream>>>(
      hid_h, hid_l, 1536, w2t_h, w2t_l, 3072, mlp_b2, nullptr, x1h, x1l, 0,
      out, nullptr, nullptr, 768, 1536);
  gemm_split<2><<<dim3(12, 64), dim3(256), 0, stream>>>(
      x1h, x1l, 768, w1t_h + (size_t)1536 * 768, w1t_l + (size_t)1536 * 768, 768,
      mlp_b1 + 1536, nullptr, nullptr, nullptr, 0, nullptr, hid_h, hid_l, 1536, 768);
  gemm_split<3><<<dim3(6, 64), dim3(256), 0, stream>>>(
      hid_h, hid_l, 1536, w2t_h + 1536, w2t_l + 1536, 3072,
      nullptr, nullptr, nullptr, nullptr, 1, out, nullptr, nullptr, 768, 1536);

  // ---- MoE (sparse top-2, segment-mapped, dbuf + XCD-chunked) ----
  ln_kernel<<<dim3(2048), dim3(256), 0, stream>>>(out, ln2g, ln2b, xmh, xml);
  gate_kernel<<<dim3(32), dim3(256), 0, stream>>>(xmh, xml, gate_w, gate_b, comb);
  listbuild_kernel<<<dim3(1), dim3(1024), 0, stream>>>(comb, lists, cnts, starts);
  etrans_kernel<<<dim3(96, 24, 4), dim3(256), 0, stream>>>(exp_w1, etw1, 768, 3072);
  etrans_kernel<<<dim3(24, 96, 4), dim3(256), 0, stream>>>(exp_w2, etw2, 3072, 768);
  for (int hf = 0; hf < 2; hf++) {
    gemm_moe1<<<dim3(1584), dim3(256), 0, stream>>>(
        xmh, etw1, exp_b1, lists, cnts, starts, ehid, hf);
    gemm_moe2<<<dim3(792), dim3(256), 0, stream>>>(
        ehid, etw2, exp_b2, comb, lists, cnts, starts, out, hf);
  }
}